// Round 1
// baseline (3761.881 us; speedup 1.0000x reference)
//
#include <hip/hip_runtime.h>

#define B_    8
#define N_    1024
#define K_    32
#define CIN   128
#define COUT  256
#define CSIPF 8
#define HEADS 4
#define EPSF  1e-5f
#define NEG   0.2f

// workspace layout (float offsets)
#define WS_M1   0      // 8   : sum of sipf
#define WS_M2   8      // 64  : sum of sipf outer products (full 8x8)
#define WS_ESUM 72     // 256 : z_pre channel sums
#define WS_ESS  328    // 256 : z_pre channel sum-squares
#define WS_Z    1024   // 8192*256 : z_pre buffer

constexpr int   P_TOT = B_ * N_ * K_;          // 262144 positions
constexpr float INV_P = 1.0f / (float)P_TOT;
constexpr int   BN_TOT = B_ * N_;              // 8192
constexpr float INV_BN = 1.0f / (float)BN_TOT;

// ---------------------------------------------------------------------------
// Kernel 1: second moments of SiPF over all (b,n,k) positions
// ---------------------------------------------------------------------------
__global__ __launch_bounds__(256) void moments_kernel(
    const float* __restrict__ SiPF, float* __restrict__ ws)
{
    float s1[8];
    float s2[36];
#pragma unroll
    for (int i = 0; i < 8; ++i) s1[i] = 0.f;
#pragma unroll
    for (int i = 0; i < 36; ++i) s2[i] = 0.f;

    const int tid = blockIdx.x * 256 + threadIdx.x;   // grid 128 -> 32768 threads
    for (int it = 0; it < P_TOT / 32768; ++it) {
        const int p = tid + it * 32768;
        const float4* base = (const float4*)(SiPF + (size_t)p * 8);
        float4 a = base[0], b = base[1];
        float v[8] = {a.x, a.y, a.z, a.w, b.x, b.y, b.z, b.w};
        int idx = 0;
#pragma unroll
        for (int i = 0; i < 8; ++i) {
            s1[i] += v[i];
#pragma unroll
            for (int j = i; j < 8; ++j) s2[idx++] += v[i] * v[j];
        }
    }
    // wave (64-lane) butterfly reduce, then lane0 atomics
#pragma unroll
    for (int i = 0; i < 8; ++i)
        for (int m = 32; m; m >>= 1) s1[i] += __shfl_xor(s1[i], m);
#pragma unroll
    for (int i = 0; i < 36; ++i)
        for (int m = 32; m; m >>= 1) s2[i] += __shfl_xor(s2[i], m);

    if ((threadIdx.x & 63) == 0) {
#pragma unroll
        for (int i = 0; i < 8; ++i) atomicAdd(&ws[WS_M1 + i], s1[i]);
        int idx = 0;
#pragma unroll
        for (int i = 0; i < 8; ++i)
#pragma unroll
            for (int j = i; j < 8; ++j) {
                float v = s2[idx++];
                atomicAdd(&ws[WS_M2 + i * 8 + j], v);
                if (i != j) atomicAdd(&ws[WS_M2 + j * 8 + i], v);
            }
    }
}

// ---------------------------------------------------------------------------
// Kernel 2: fused main — one block per (b,n)
// ---------------------------------------------------------------------------
__global__ __launch_bounds__(256) void main_kernel(
    const float* __restrict__ x,    const float* __restrict__ SiPF,
    const float* __restrict__ w_kv, const float* __restrict__ wk1,
    const float* __restrict__ bnk_gamma, const float* __restrict__ bnk_beta,
    const float* __restrict__ wk2,  const float* __restrict__ wv1,
    const float* __restrict__ bnv_gamma, const float* __restrict__ bnv_beta,
    const float* __restrict__ wv2,  const float* __restrict__ bv2,
    const float* __restrict__ we,   const int* __restrict__ col,
    const float* __restrict__ ws,   float* __restrict__ z_ws)
{
    __shared__ __align__(16) float s_fs[CIN * K_];   // gathered x columns
    __shared__ __align__(16) float s_hk[CIN * K_];
    __shared__ __align__(16) float s_hv[CIN * K_];
    __shared__ __align__(16) float s_q [CIN * K_];
    __shared__ __align__(16) float s_kk[CIN * K_];
    __shared__ __align__(16) float s_v [CIN * K_];   // vfs, then v = vfs*vsipf
    __shared__ float s_Ak[CIN], s_Bk[CIN], s_Av[CIN], s_Bv[CIN];
    __shared__ float s_y[CIN], s_x[CIN];

    const int bn = blockIdx.x;
    const int b  = bn >> 10;
    const int n  = bn & (N_ - 1);
    const int t  = threadIdx.x;
    const int k  = t & 31;
    const int cg = t >> 5;            // 0..7

    // per-thread sipf row (k fixed): 8 floats
    const float4* sp = (const float4*)(SiPF + (size_t)bn * K_ * CSIPF + k * CSIPF);
    float4 sa = sp[0], sb = sp[1];
    float sip[8] = {sa.x, sa.y, sa.z, sa.w, sb.x, sb.y, sb.z, sb.w};

    // gather index for this k
    const int idxk = col[bn * K_ + k] - b * N_;

    // issue gather loads early (16 channels per thread)
    float fsv[16];
#pragma unroll
    for (int i = 0; i < 16; ++i) {
        const int c = cg * 16 + i;
        fsv[i] = x[((size_t)(b * CIN + c)) * N_ + idxk];
    }

    // BN-fold coefficients from SiPF moments (threads 0..127, one channel each)
    if (t < CIN) {
        const int c = t;
        float m1[8], wkr[8], wvr[8];
#pragma unroll
        for (int s = 0; s < 8; ++s) {
            m1[s]  = ws[WS_M1 + s] * INV_P;
            wkr[s] = wk1[c * 8 + s];
            wvr[s] = wv1[c * 8 + s];
        }
        float mk = 0.f, mv = 0.f;
#pragma unroll
        for (int s = 0; s < 8; ++s) { mk += wkr[s] * m1[s]; mv += wvr[s] * m1[s]; }
        float ek = 0.f, ev = 0.f;
#pragma unroll
        for (int s = 0; s < 8; ++s)
#pragma unroll
            for (int s2 = 0; s2 < 8; ++s2) {
                const float m2 = ws[WS_M2 + s * 8 + s2] * INV_P;
                ek += wkr[s] * wkr[s2] * m2;
                ev += wvr[s] * wvr[s2] * m2;
            }
        const float vark = ek - mk * mk;
        const float varv = ev - mv * mv;
        const float Ak = bnk_gamma[c] * rsqrtf(vark + EPSF);
        const float Av = bnv_gamma[c] * rsqrtf(varv + EPSF);
        s_Ak[c] = Ak; s_Bk[c] = bnk_beta[c] - mk * Ak;   // bv1 cancels in BN
        s_Av[c] = Av; s_Bv[c] = bnv_beta[c] - mv * Av;
        s_x[c] = x[((size_t)(b * CIN + c)) * N_ + n];
    }
    __syncthreads();

    // hk = relu(Ak * (wk1 @ sipf) + Bk); hv likewise; store fs
#pragma unroll
    for (int i = 0; i < 16; ++i) {
        const int c = cg * 16 + i;
        float ak = 0.f, av = 0.f;
#pragma unroll
        for (int s = 0; s < 8; ++s) {
            ak += wk1[c * 8 + s] * sip[s];
            av += wv1[c * 8 + s] * sip[s];
        }
        const float hkv = s_Ak[c] * ak + s_Bk[c];
        const float hvv = s_Av[c] * av + s_Bv[c];
        s_hk[c * 32 + k] = hkv > 0.f ? hkv : 0.f;
        s_hv[c * 32 + k] = hvv > 0.f ? hvv : 0.f;
        s_fs[c * 32 + k] = fsv[i];
    }
    __syncthreads();

    // q = Wq @ fs ; vfs = Wv @ fs   (thread owns k, 16 output channels)
    float accq[16], accv[16];
#pragma unroll
    for (int i = 0; i < 16; ++i) { accq[i] = 0.f; accv[i] = 0.f; }
    for (int cp = 0; cp < CIN; cp += 4) {
        const float f0 = s_fs[(cp + 0) * 32 + k];
        const float f1 = s_fs[(cp + 1) * 32 + k];
        const float f2 = s_fs[(cp + 2) * 32 + k];
        const float f3 = s_fs[(cp + 3) * 32 + k];
#pragma unroll
        for (int i = 0; i < 16; ++i) {
            const int c = cg * 16 + i;
            const float4 wq = *(const float4*)&w_kv[(size_t)c * CIN + cp];
            const float4 wv4 = *(const float4*)&w_kv[(size_t)(CIN + c) * CIN + cp];
            accq[i] += wq.x * f0 + wq.y * f1 + wq.z * f2 + wq.w * f3;
            accv[i] += wv4.x * f0 + wv4.y * f1 + wv4.z * f2 + wv4.w * f3;
        }
    }
#pragma unroll
    for (int i = 0; i < 16; ++i) {
        const int c = cg * 16 + i;
        s_q[c * 32 + k] = accq[i];
        s_v[c * 32 + k] = accv[i];   // vfs for now
    }

    // kk = wk2 @ hk ; vsipf = wv2 @ hv + bv2 ; v = vfs * vsipf
    float acck[16], accs[16];
#pragma unroll
    for (int i = 0; i < 16; ++i) { acck[i] = 0.f; accs[i] = 0.f; }
    for (int cp = 0; cp < CIN; cp += 4) {
        const float h0 = s_hk[(cp + 0) * 32 + k];
        const float h1 = s_hk[(cp + 1) * 32 + k];
        const float h2 = s_hk[(cp + 2) * 32 + k];
        const float h3 = s_hk[(cp + 3) * 32 + k];
        const float g0 = s_hv[(cp + 0) * 32 + k];
        const float g1 = s_hv[(cp + 1) * 32 + k];
        const float g2 = s_hv[(cp + 2) * 32 + k];
        const float g3 = s_hv[(cp + 3) * 32 + k];
#pragma unroll
        for (int i = 0; i < 16; ++i) {
            const int c = cg * 16 + i;
            const float4 w1 = *(const float4*)&wk2[(size_t)c * CIN + cp];
            const float4 w2 = *(const float4*)&wv2[(size_t)c * CIN + cp];
            acck[i] += w1.x * h0 + w1.y * h1 + w1.z * h2 + w1.w * h3;
            accs[i] += w2.x * g0 + w2.y * g1 + w2.z * g2 + w2.w * g3;
        }
    }
#pragma unroll
    for (int i = 0; i < 16; ++i) {
        const int c = cg * 16 + i;
        s_kk[c * 32 + k] = acck[i];
        s_v[c * 32 + k]  = accv[i] * (accs[i] + bv2[c]);   // v = vfs * vsipf
    }
    __syncthreads();

    // ---- attention: one head per wave; thread owns score-row kq ----
    const int h  = t >> 6;
    const int r  = t & 63;
    const int kq = r & 31;
    const int dh = r >> 5;

    float sc[32];
#pragma unroll
    for (int j = 0; j < 32; ++j) sc[j] = 0.f;
#pragma unroll 4
    for (int d = 0; d < 32; ++d) {
        const float qd = s_q[(h * 32 + d) * 32 + kq];
        const float4* kr = (const float4*)&s_kk[(h * 32 + d) * 32];
#pragma unroll
        for (int j4 = 0; j4 < 8; ++j4) {
            const float4 kv = kr[j4];
            sc[4 * j4 + 0] += qd * kv.x;
            sc[4 * j4 + 1] += qd * kv.y;
            sc[4 * j4 + 2] += qd * kv.z;
            sc[4 * j4 + 3] += qd * kv.w;
        }
    }
    const float scale = 0.17677669529663687f;   // 1/sqrt(32)
    float mx = -1e30f;
#pragma unroll
    for (int j = 0; j < 32; ++j) { sc[j] *= scale; mx = fmaxf(mx, sc[j]); }
    float ssum = 0.f;
#pragma unroll
    for (int j = 0; j < 32; ++j) { sc[j] = __expf(sc[j] - mx); ssum += sc[j]; }
    const float inv = 1.0f / ssum;
#pragma unroll
    for (int j = 0; j < 32; ++j) sc[j] *= inv;

    float od[16];
#pragma unroll
    for (int d16 = 0; d16 < 16; ++d16) {
        const int c = h * 32 + dh * 16 + d16;
        const float4* vr = (const float4*)&s_v[c * 32];
        float acc = 0.f;
#pragma unroll
        for (int j4 = 0; j4 < 8; ++j4) {
            const float4 vv = vr[j4];
            acc += sc[4 * j4 + 0] * vv.x + sc[4 * j4 + 1] * vv.y +
                   sc[4 * j4 + 2] * vv.z + sc[4 * j4 + 3] * vv.w;
        }
        od[d16] = acc;
    }
    // max over kq (lane bits 0..4) via butterfly
#pragma unroll
    for (int m = 1; m <= 16; m <<= 1)
#pragma unroll
        for (int d16 = 0; d16 < 16; ++d16)
            od[d16] = fmaxf(od[d16], __shfl_xor(od[d16], m));
    if (kq == 0) {
#pragma unroll
        for (int d16 = 0; d16 < 16; ++d16)
            s_y[h * 32 + dh * 16 + d16] = od[d16];
    }
    __syncthreads();

    // ---- z_pre[o] = we[o,:128]·(y-x) + we[o,128:]·x ----
    {
        const int o = t;
        const float4* w1 = (const float4*)&we[(size_t)o * COUT];
        const float4* w2 = (const float4*)&we[(size_t)o * COUT + CIN];
        float acc = 0.f;
#pragma unroll
        for (int c4 = 0; c4 < 32; ++c4) {
            const float4 wa = w1[c4];
            const float4 wb = w2[c4];
            const float x0 = s_x[4 * c4 + 0], x1 = s_x[4 * c4 + 1];
            const float x2 = s_x[4 * c4 + 2], x3 = s_x[4 * c4 + 3];
            const float y0 = s_y[4 * c4 + 0], y1 = s_y[4 * c4 + 1];
            const float y2 = s_y[4 * c4 + 2], y3 = s_y[4 * c4 + 3];
            acc += wa.x * (y0 - x0) + wa.y * (y1 - x1) +
                   wa.z * (y2 - x2) + wa.w * (y3 - x3);
            acc += wb.x * x0 + wb.y * x1 + wb.z * x2 + wb.w * x3;
        }
        z_ws[(size_t)bn * COUT + o] = acc;
    }
}

// ---------------------------------------------------------------------------
// Kernel 3: per-channel sum / sumsq of z_pre over (b,n)
// ---------------------------------------------------------------------------
__global__ __launch_bounds__(256) void bne_reduce_kernel(
    const float* __restrict__ z_ws, float* __restrict__ ws)
{
    const int o  = threadIdx.x;
    const int r0 = blockIdx.x * 128;   // grid 64 -> 8192 rows
    float s = 0.f, ss = 0.f;
    for (int r = 0; r < 128; ++r) {
        const float v = z_ws[(size_t)(r0 + r) * COUT + o];
        s += v;
        ss += v * v;
    }
    atomicAdd(&ws[WS_ESUM + o], s);
    atomicAdd(&ws[WS_ESS + o], ss);
}

// ---------------------------------------------------------------------------
// Kernel 4: BN1d affine + leaky relu, write (B, COUT, N) output
// ---------------------------------------------------------------------------
__global__ __launch_bounds__(256) void apply_kernel(
    const float* __restrict__ z_ws, const float* __restrict__ ws,
    const float* __restrict__ gamma, const float* __restrict__ beta,
    float* __restrict__ out)
{
    const int bn = blockIdx.x;
    const int o  = threadIdx.x;
    const int b  = bn >> 10;
    const int n  = bn & (N_ - 1);

    const float mean = ws[WS_ESUM + o] * INV_BN;
    const float var  = ws[WS_ESS + o] * INV_BN - mean * mean;
    const float A = gamma[o] * rsqrtf(var + EPSF);
    const float Bb = beta[o] - mean * A;

    const float z = z_ws[(size_t)bn * COUT + o];
    const float rv = A * z + Bb;
    out[((size_t)(b * COUT + o)) * N_ + n] = rv >= 0.f ? rv : NEG * rv;
}

// ---------------------------------------------------------------------------
extern "C" void kernel_launch(void* const* d_in, const int* in_sizes, int n_in,
                              void* d_out, int out_size, void* d_ws, size_t ws_size,
                              hipStream_t stream)
{
    (void)in_sizes; (void)n_in; (void)out_size; (void)ws_size;

    const float* x         = (const float*)d_in[0];
    const float* SiPF      = (const float*)d_in[1];
    const float* w_kv      = (const float*)d_in[2];
    const float* wk1       = (const float*)d_in[3];
    const float* bnk_gamma = (const float*)d_in[4];
    const float* bnk_beta  = (const float*)d_in[5];
    const float* wk2       = (const float*)d_in[6];
    const float* wv1       = (const float*)d_in[7];
    // d_in[8] = bv1: cancels inside _bn2d (mean subtraction) — unused
    const float* bnv_gamma = (const float*)d_in[9];
    const float* bnv_beta  = (const float*)d_in[10];
    const float* wv2       = (const float*)d_in[11];
    const float* bv2       = (const float*)d_in[12];
    const float* we        = (const float*)d_in[13];
    const float* bne_gamma = (const float*)d_in[14];
    const float* bne_beta  = (const float*)d_in[15];
    const int*   col       = (const int*)d_in[16];

    float* ws   = (float*)d_ws;
    float* z_ws = ws + WS_Z;

    // zero the accumulator region (moments + bne sums)
    hipMemsetAsync(d_ws, 0, (WS_ESS + COUT) * sizeof(float), stream);

    moments_kernel<<<128, 256, 0, stream>>>(SiPF, ws);
    main_kernel<<<B_ * N_, 256, 0, stream>>>(
        x, SiPF, w_kv, wk1, bnk_gamma, bnk_beta, wk2, wv1,
        bnv_gamma, bnv_beta, wv2, bv2, we, col, ws, z_ws);
    bne_reduce_kernel<<<64, 256, 0, stream>>>(z_ws, ws);
    apply_kernel<<<B_ * N_, 256, 0, stream>>>(z_ws, ws, bne_gamma, bne_beta,
                                              (float*)d_out);
}

// Round 2
// 505.394 us; speedup vs baseline: 7.4435x; 7.4435x over previous
//
// RINet fused kernel — R2: MFMA bf16 GEMMs + 3 blocks/CU occupancy
// Journal: R1 fp32-VALU baseline 3762us, occ 11.9% (99KB LDS, 1 blk/CU),
// VALUBusy 23.7%, MfmaUtil 0. R2: mfma_f32_16x16x32_bf16 for the 4 GEMMs,
// LDS 51KB bf16 tiles (3 blk/CU), swizzled [k][c] staging, shfl-split attn.
#include <hip/hip_runtime.h>

#define B_    8
#define N_    1024
#define K_    32
#define CIN   128
#define COUT  256
#define EPSF  1e-5f
#define NEG   0.2f

// ws float-offset layout
#define WS_M1   0        // 8   : sum sipf
#define WS_M2   8        // 64  : sum sipf outer (full 8x8)
#define WS_ESUM 72       // 256 : z channel sums
#define WS_ESS  328      // 256 : z channel sumsq
#define WS_ZU   1024     // ushort z_pre[8192][256] (4 MB)
#define WS_WB   (1024 + 1048576)  // bf16 weights region (256 KB)
// short offsets inside wb
#define WQB  0
#define WVB  16384
#define WK2B 32768
#define WV2B 49152
#define WEB  65536

typedef unsigned short ushort_t;
typedef unsigned int   uint_t;
typedef __attribute__((ext_vector_type(8))) short s8v;
typedef __attribute__((ext_vector_type(4))) float f4v;
typedef __bf16 bf16x8 __attribute__((ext_vector_type(8)));

constexpr int   P_TOT  = B_ * N_ * K_;          // 262144
constexpr float INV_P  = 1.0f / (float)P_TOT;
constexpr float INV_BN = 1.0f / (float)(B_ * N_);

__device__ __forceinline__ float b2f(ushort_t u) {
    return __uint_as_float(((uint_t)u) << 16);
}
__device__ __forceinline__ ushort_t f2b(float f) {
    uint_t u = __float_as_uint(f);
    u += 0x7fffu + ((u >> 16) & 1u);            // RNE
    return (ushort_t)(u >> 16);
}
__device__ __forceinline__ bf16x8 ld8(const ushort_t* p) {
    return __builtin_bit_cast(bf16x8, *(const s8v*)p);
}
// swizzled index for [c][32] bf16 tiles (q/kk/v): spreads D-frag row writes
__device__ __forceinline__ int qx(int c, int k) {
    return (c * 32 + k) ^ (((c >> 2) & 3) << 3);
}

// ---------------------------------------------------------------------------
// prep: fp32 weights -> bf16 region in ws
// ---------------------------------------------------------------------------
__global__ __launch_bounds__(256) void prep_kernel(
    const float* __restrict__ w_kv, const float* __restrict__ wk2,
    const float* __restrict__ wv2,  const float* __restrict__ we,
    ushort_t* __restrict__ wb)
{
    const int tid = blockIdx.x * 256 + threadIdx.x;   // grid 128
#pragma unroll
    for (int i = 0; i < 4; ++i) {
        const int e = tid + i * 32768;
        float v;
        if (e < 32768)      v = w_kv[e];              // rows 0..127=Wq,128..255=Wv
        else if (e < 49152) v = wk2[e - 32768];
        else if (e < 65536) v = wv2[e - 49152];
        else                v = we[e - 65536];
        wb[e] = f2b(v);
    }
}

// ---------------------------------------------------------------------------
// moments of SiPF (block-local reduce -> few atomics)
// ---------------------------------------------------------------------------
__global__ __launch_bounds__(256) void moments_kernel(
    const float* __restrict__ SiPF, float* __restrict__ ws)
{
    __shared__ float red[4][44];
    float s1[8];
    float s2[36];
#pragma unroll
    for (int i = 0; i < 8; ++i) s1[i] = 0.f;
#pragma unroll
    for (int i = 0; i < 36; ++i) s2[i] = 0.f;

    const int tid = blockIdx.x * 256 + threadIdx.x;   // grid 64 -> 16384 thr
    for (int it = 0; it < P_TOT / 16384; ++it) {
        const int p = tid + it * 16384;
        const float4* base = (const float4*)(SiPF + (size_t)p * 8);
        float4 a = base[0], bq = base[1];
        float v[8] = {a.x, a.y, a.z, a.w, bq.x, bq.y, bq.z, bq.w};
        int idx = 0;
#pragma unroll
        for (int i = 0; i < 8; ++i) {
            s1[i] += v[i];
#pragma unroll
            for (int j = i; j < 8; ++j) s2[idx++] += v[i] * v[j];
        }
    }
#pragma unroll
    for (int i = 0; i < 8; ++i)
        for (int m = 32; m; m >>= 1) s1[i] += __shfl_xor(s1[i], m);
#pragma unroll
    for (int i = 0; i < 36; ++i)
        for (int m = 32; m; m >>= 1) s2[i] += __shfl_xor(s2[i], m);

    const int t = threadIdx.x;
    if ((t & 63) == 0) {
        const int w = t >> 6;
#pragma unroll
        for (int i = 0; i < 8; ++i) red[w][i] = s1[i];
#pragma unroll
        for (int i = 0; i < 36; ++i) red[w][8 + i] = s2[i];
    }
    __syncthreads();
    if (t < 44) {
        const float v = red[0][t] + red[1][t] + red[2][t] + red[3][t];
        if (t < 8) atomicAdd(&ws[WS_M1 + t], v);
        else {
            int p = t - 8, i = 0, row = 8;
            while (p >= row) { p -= row; --row; ++i; }
            const int j = i + p;
            atomicAdd(&ws[WS_M2 + i * 8 + j], v);
            if (i != j) atomicAdd(&ws[WS_M2 + j * 8 + i], v);
        }
    }
}

// ---------------------------------------------------------------------------
// main fused kernel — one block per (b,n), 4 waves
// ---------------------------------------------------------------------------
__global__ __launch_bounds__(256, 3) void main_kernel(
    const float* __restrict__ x,    const float* __restrict__ SiPF,
    const float* __restrict__ wk1,  const float* __restrict__ wv1,
    const float* __restrict__ bnk_gamma, const float* __restrict__ bnk_beta,
    const float* __restrict__ bnv_gamma, const float* __restrict__ bnv_beta,
    const float* __restrict__ bv2,  const int* __restrict__ col,
    const float* __restrict__ ws,   const ushort_t* __restrict__ wb,
    ushort_t* __restrict__ z_u)
{
    // staging tiles [k=32][c=128] bf16, idx ^= (k&7)<<3  (bank-spread for B-frags)
    __shared__ __align__(16) ushort_t s_fsT[4096];
    __shared__ __align__(16) ushort_t s_hkT[4096];
    __shared__ __align__(16) ushort_t s_hvT[4096];
    // result tiles [c=128][k=32] bf16, idx via qx()
    __shared__ __align__(16) ushort_t s_q [4096];
    __shared__ __align__(16) ushort_t s_kk[4096];
    __shared__ __align__(16) ushort_t s_v [4096];
    __shared__ float s_Ak[CIN], s_Bk[CIN], s_Av[CIN], s_Bv[CIN];
    __shared__ float s_bv2[CIN];
    __shared__ __align__(16) float s_x[CIN], s_y[CIN];

    const int bn = blockIdx.x;
    const int b  = bn >> 10;
    const int n  = bn & (N_ - 1);
    const int t  = threadIdx.x;

    // ---------------- Phase A: sipf, gather, BN-fold coeffs -----------------
    const int k  = t & 31;
    const int cg = t >> 5;                         // 0..7

    const float4* sp = (const float4*)(SiPF + (size_t)bn * K_ * 8 + k * 8);
    float4 sa = sp[0], sb = sp[1];
    float sip[8] = {sa.x, sa.y, sa.z, sa.w, sb.x, sb.y, sb.z, sb.w};

    const int idxk = col[bn * K_ + k] - b * N_;
    float fsv[16];
#pragma unroll
    for (int i = 0; i < 16; ++i)
        fsv[i] = x[((size_t)(b * CIN + cg * 16 + i)) * N_ + idxk];

    if (t < CIN) {
        const int c = t;
        float m1[8], wkr[8], wvr[8];
#pragma unroll
        for (int s = 0; s < 8; ++s) {
            m1[s]  = ws[WS_M1 + s] * INV_P;
            wkr[s] = wk1[c * 8 + s];
            wvr[s] = wv1[c * 8 + s];
        }
        float mk = 0.f, mv = 0.f;
#pragma unroll
        for (int s = 0; s < 8; ++s) { mk += wkr[s] * m1[s]; mv += wvr[s] * m1[s]; }
        float ek = 0.f, ev = 0.f;
#pragma unroll
        for (int s = 0; s < 8; ++s)
#pragma unroll
            for (int s2 = 0; s2 < 8; ++s2) {
                const float m2 = ws[WS_M2 + s * 8 + s2] * INV_P;
                ek += wkr[s] * wkr[s2] * m2;
                ev += wvr[s] * wvr[s2] * m2;
            }
        const float Ak = bnk_gamma[c] * rsqrtf(ek - mk * mk + EPSF);
        const float Av = bnv_gamma[c] * rsqrtf(ev - mv * mv + EPSF);
        s_Ak[c] = Ak; s_Bk[c] = bnk_beta[c] - mk * Ak;   // bv1 cancels in BN
        s_Av[c] = Av; s_Bv[c] = bnv_beta[c] - mv * Av;
        s_bv2[c] = bv2[c];
        s_x[c] = x[((size_t)(b * CIN + c)) * N_ + n];
    }
    __syncthreads();

    // hk/hv (K=8 VALU GEMM) + fs -> bf16 swizzled LDS [k][c]
#pragma unroll
    for (int i = 0; i < 16; i += 2) {
        const int c = cg * 16 + i;
        float ak0 = 0.f, av0 = 0.f, ak1 = 0.f, av1 = 0.f;
#pragma unroll
        for (int s = 0; s < 8; ++s) {
            ak0 += wk1[c * 8 + s] * sip[s];
            av0 += wv1[c * 8 + s] * sip[s];
            ak1 += wk1[(c + 1) * 8 + s] * sip[s];
            av1 += wv1[(c + 1) * 8 + s] * sip[s];
        }
        const float hk0 = fmaxf(s_Ak[c] * ak0 + s_Bk[c], 0.f);
        const float hk1 = fmaxf(s_Ak[c + 1] * ak1 + s_Bk[c + 1], 0.f);
        const float hv0 = fmaxf(s_Av[c] * av0 + s_Bv[c], 0.f);
        const float hv1 = fmaxf(s_Av[c + 1] * av1 + s_Bv[c + 1], 0.f);
        const int idx = (k * CIN + c) ^ ((k & 7) << 3);   // even, pair-contig
        *(uint_t*)&s_hkT[idx] = (uint_t)f2b(hk0) | ((uint_t)f2b(hk1) << 16);
        *(uint_t*)&s_hvT[idx] = (uint_t)f2b(hv0) | ((uint_t)f2b(hv1) << 16);
        *(uint_t*)&s_fsT[idx] = (uint_t)f2b(fsv[i]) | ((uint_t)f2b(fsv[i + 1]) << 16);
    }
    __syncthreads();

    // ---------------- Phase B: q = Wq@fs, vfs = Wv@fs  (MFMA) ---------------
    const int wv_ = t >> 6;                      // wave = output row block
    const int l   = t & 63;
    const int lr  = l & 15;
    const int lg  = l >> 4;

    const ushort_t* wqb  = wb + WQB;
    const ushort_t* wvb  = wb + WVB;
    const ushort_t* wk2b = wb + WK2B;
    const ushort_t* wv2b = wb + WV2B;

    const f4v z4 = {0.f, 0.f, 0.f, 0.f};
    f4v aq[2][2], av[2][2];
#pragma unroll
    for (int mi = 0; mi < 2; ++mi)
#pragma unroll
        for (int ni = 0; ni < 2; ++ni) { aq[mi][ni] = z4; av[mi][ni] = z4; }

#pragma unroll
    for (int kt = 0; kt < 4; ++kt) {
        const int cp0 = kt * 32 + lg * 8;
        bf16x8 bfr[2];
#pragma unroll
        for (int ni = 0; ni < 2; ++ni) {
            const int kk_ = ni * 16 + lr;
            bfr[ni] = ld8(&s_fsT[(kk_ * CIN + cp0) ^ ((kk_ & 7) << 3)]);
        }
#pragma unroll
        for (int mi = 0; mi < 2; ++mi) {
            const int c = wv_ * 32 + mi * 16 + lr;
            const bf16x8 a1 = ld8(&wqb[c * CIN + cp0]);
            const bf16x8 a2 = ld8(&wvb[c * CIN + cp0]);
#pragma unroll
            for (int ni = 0; ni < 2; ++ni) {
                aq[mi][ni] = __builtin_amdgcn_mfma_f32_16x16x32_bf16(a1, bfr[ni], aq[mi][ni], 0, 0, 0);
                av[mi][ni] = __builtin_amdgcn_mfma_f32_16x16x32_bf16(a2, bfr[ni], av[mi][ni], 0, 0, 0);
            }
        }
    }
    // D layout: col = ni*16 + (l&15), row = mi*16 + lg*4 + r
#pragma unroll
    for (int mi = 0; mi < 2; ++mi)
#pragma unroll
        for (int ni = 0; ni < 2; ++ni)
#pragma unroll
            for (int r = 0; r < 4; ++r) {
                const int c   = wv_ * 32 + mi * 16 + lg * 4 + r;
                const int kk_ = ni * 16 + lr;
                s_q[qx(c, kk_)] = f2b(aq[mi][ni][r]);
            }

    // ---------------- Phase C: kk = wk2@hk, v = vfs*(wv2@hv + bv2) ----------
    f4v ck[2][2], cs[2][2];
#pragma unroll
    for (int mi = 0; mi < 2; ++mi)
#pragma unroll
        for (int ni = 0; ni < 2; ++ni) { ck[mi][ni] = z4; cs[mi][ni] = z4; }

#pragma unroll
    for (int kt = 0; kt < 4; ++kt) {
        const int cp0 = kt * 32 + lg * 8;
        bf16x8 bk[2], bv[2];
#pragma unroll
        for (int ni = 0; ni < 2; ++ni) {
            const int kk_ = ni * 16 + lr;
            const int idx = (kk_ * CIN + cp0) ^ ((kk_ & 7) << 3);
            bk[ni] = ld8(&s_hkT[idx]);
            bv[ni] = ld8(&s_hvT[idx]);
        }
#pragma unroll
        for (int mi = 0; mi < 2; ++mi) {
            const int c = wv_ * 32 + mi * 16 + lr;
            const bf16x8 a1 = ld8(&wk2b[c * CIN + cp0]);
            const bf16x8 a2 = ld8(&wv2b[c * CIN + cp0]);
#pragma unroll
            for (int ni = 0; ni < 2; ++ni) {
                ck[mi][ni] = __builtin_amdgcn_mfma_f32_16x16x32_bf16(a1, bk[ni], ck[mi][ni], 0, 0, 0);
                cs[mi][ni] = __builtin_amdgcn_mfma_f32_16x16x32_bf16(a2, bv[ni], cs[mi][ni], 0, 0, 0);
            }
        }
    }
#pragma unroll
    for (int mi = 0; mi < 2; ++mi)
#pragma unroll
        for (int ni = 0; ni < 2; ++ni)
#pragma unroll
            for (int r = 0; r < 4; ++r) {
                const int c   = wv_ * 32 + mi * 16 + lg * 4 + r;
                const int kk_ = ni * 16 + lr;
                s_kk[qx(c, kk_)] = f2b(ck[mi][ni][r]);
                const float vvv = av[mi][ni][r] * (cs[mi][ni][r] + s_bv2[c]);
                s_v[qx(c, kk_)] = f2b(vvv);
            }
    __syncthreads();

    // ---------------- Phase D: attention (head = wave) ----------------------
    const int h  = t >> 6;
    const int r_ = t & 63;
    const int kq = r_ & 31;
    const int dh = r_ >> 5;
    const int j0 = dh * 16;                       // this half's j range

    float scl[16];
#pragma unroll
    for (int j = 0; j < 16; ++j) scl[j] = 0.f;
#pragma unroll 4
    for (int d = 0; d < 32; ++d) {
        const int c = h * 32 + d;
        const float qd = b2f(s_q[qx(c, kq)]);
        const s8v kv0 = *(const s8v*)&s_kk[qx(c, j0)];
        const s8v kv1 = *(const s8v*)&s_kk[qx(c, j0 + 8)];
#pragma unroll
        for (int jj = 0; jj < 8; ++jj) {
            scl[jj]     += qd * b2f((ushort_t)kv0[jj]);
            scl[8 + jj] += qd * b2f((ushort_t)kv1[jj]);
        }
    }
    // exchange halves with partner lane (dh flipped)
    float row[32];
#pragma unroll
    for (int jj = 0; jj < 16; ++jj) {
        const float o = __shfl_xor(scl[jj], 32);
        row[j0 + jj]        = scl[jj];
        row[(j0 ^ 16) + jj] = o;
    }
    const float scale = 0.17677669529663687f;     // 1/sqrt(32)
    float mx = -1e30f;
#pragma unroll
    for (int j = 0; j < 32; ++j) { row[j] *= scale; mx = fmaxf(mx, row[j]); }
    float ssum = 0.f;
#pragma unroll
    for (int j = 0; j < 32; ++j) { row[j] = __expf(row[j] - mx); ssum += row[j]; }
    const float inv = 1.0f / ssum;
#pragma unroll
    for (int j = 0; j < 32; ++j) row[j] *= inv;

    float od[16];
#pragma unroll
    for (int d16 = 0; d16 < 16; ++d16) {
        const int c = h * 32 + dh * 16 + d16;
        float acc = 0.f;
#pragma unroll
        for (int j8 = 0; j8 < 4; ++j8) {
            const s8v vv = *(const s8v*)&s_v[qx(c, j8 * 8)];
#pragma unroll
            for (int jj = 0; jj < 8; ++jj)
                acc += row[j8 * 8 + jj] * b2f((ushort_t)vv[jj]);
        }
        od[d16] = acc;
    }
#pragma unroll
    for (int m = 1; m <= 16; m <<= 1)
#pragma unroll
        for (int d16 = 0; d16 < 16; ++d16)
            od[d16] = fmaxf(od[d16], __shfl_xor(od[d16], m));
    if (kq == 0) {
#pragma unroll
        for (int d16 = 0; d16 < 16; ++d16)
            s_y[h * 32 + dh * 16 + d16] = od[d16];
    }
    __syncthreads();

    // ---------------- Phase E: z_pre = we·cat(y-x, x) (bf16 weights) --------
    {
        const int o = t;
        const ushort_t* wrow = wb + WEB + o * 256;
        float acc = 0.f;
#pragma unroll 4
        for (int c8 = 0; c8 < 16; ++c8) {
            const s8v w8 = *(const s8v*)&wrow[c8 * 8];
#pragma unroll
            for (int j = 0; j < 8; ++j) {
                const int cc = c8 * 8 + j;
                acc += b2f((ushort_t)w8[j]) * (s_y[cc] - s_x[cc]);
            }
        }
#pragma unroll 4
        for (int c8 = 0; c8 < 16; ++c8) {
            const s8v w8 = *(const s8v*)&wrow[CIN + c8 * 8];
#pragma unroll
            for (int j = 0; j < 8; ++j)
                acc += b2f((ushort_t)w8[j]) * s_x[c8 * 8 + j];
        }
        z_u[(size_t)bn * COUT + o] = f2b(acc);
    }
}

// ---------------------------------------------------------------------------
// bne stats over z_pre
// ---------------------------------------------------------------------------
__global__ __launch_bounds__(256) void bne_reduce_kernel(
    const ushort_t* __restrict__ z_u, float* __restrict__ ws)
{
    const int o  = threadIdx.x;
    const int r0 = blockIdx.x * 128;              // grid 64
    float s = 0.f, ss = 0.f;
    for (int r = 0; r < 128; ++r) {
        const float v = b2f(z_u[(size_t)(r0 + r) * COUT + o]);
        s += v; ss += v * v;
    }
    atomicAdd(&ws[WS_ESUM + o], s);
    atomicAdd(&ws[WS_ESS + o], ss);
}

// ---------------------------------------------------------------------------
// final BN1d + leaky relu -> out (B, COUT, N), coalesced writes
// ---------------------------------------------------------------------------
__global__ __launch_bounds__(256) void apply_kernel(
    const ushort_t* __restrict__ z_u, const float* __restrict__ ws,
    const float* __restrict__ gamma, const float* __restrict__ beta,
    float* __restrict__ out)
{
    const int bo = blockIdx.x;                    // grid B*COUT = 2048
    const int b  = bo >> 8;
    const int o  = bo & 255;
    const float mean = ws[WS_ESUM + o] * INV_BN;
    const float var  = ws[WS_ESS + o] * INV_BN - mean * mean;
    const float A  = gamma[o] * rsqrtf(var + EPSF);
    const float Bb = beta[o] - mean * A;
    const int t = threadIdx.x;
#pragma unroll
    for (int i = 0; i < 4; ++i) {
        const int n = i * 256 + t;
        const float z  = b2f(z_u[(size_t)(b * N_ + n) * COUT + o]);
        const float rv = A * z + Bb;
        out[((size_t)(b * COUT + o)) * N_ + n] = rv >= 0.f ? rv : NEG * rv;
    }
}

// ---------------------------------------------------------------------------
extern "C" void kernel_launch(void* const* d_in, const int* in_sizes, int n_in,
                              void* d_out, int out_size, void* d_ws, size_t ws_size,
                              hipStream_t stream)
{
    (void)in_sizes; (void)n_in; (void)out_size; (void)ws_size;

    const float* x         = (const float*)d_in[0];
    const float* SiPF      = (const float*)d_in[1];
    const float* w_kv      = (const float*)d_in[2];
    const float* wk1       = (const float*)d_in[3];
    const float* bnk_gamma = (const float*)d_in[4];
    const float* bnk_beta  = (const float*)d_in[5];
    const float* wk2       = (const float*)d_in[6];
    const float* wv1       = (const float*)d_in[7];
    // d_in[8] = bv1: cancels inside _bn2d — unused
    const float* bnv_gamma = (const float*)d_in[9];
    const float* bnv_beta  = (const float*)d_in[10];
    const float* wv2       = (const float*)d_in[11];
    const float* bv2       = (const float*)d_in[12];
    const float* we        = (const float*)d_in[13];
    const float* bne_gamma = (const float*)d_in[14];
    const float* bne_beta  = (const float*)d_in[15];
    const int*   col       = (const int*)d_in[16];

    float*    ws  = (float*)d_ws;
    ushort_t* z_u = (ushort_t*)(ws + WS_ZU);
    ushort_t* wb  = (ushort_t*)(ws + WS_WB);

    hipMemsetAsync(d_ws, 0, (WS_ESS + COUT) * sizeof(float), stream);

    prep_kernel<<<128, 256, 0, stream>>>(w_kv, wk2, wv2, we, wb);
    moments_kernel<<<64, 256, 0, stream>>>(SiPF, ws);
    main_kernel<<<B_ * N_, 256, 0, stream>>>(
        x, SiPF, wk1, wv1, bnk_gamma, bnk_beta, bnv_gamma, bnv_beta,
        bv2, col, ws, wb, z_u);
    bne_reduce_kernel<<<64, 256, 0, stream>>>(z_u, ws);
    apply_kernel<<<2048, 256, 0, stream>>>(z_u, ws, bne_gamma, bne_beta,
                                           (float*)d_out);
}

// Round 3
// 312.263 us; speedup vs baseline: 12.0472x; 1.6185x over previous
//
// RINet fused — R3: MFMA attention + zgemm epilogue + xT gather
// Journal: R1 3762us (fp32 VALU, 1blk/CU). R2 505us (MFMA GEMMs, but attn+
// epilogue VALU-bound: VALUBusy 73%, MfmaUtil 2.9%, 84MB scratch from
// runtime-indexed row[32]). R3: attention via 16x16x32 MFMA (qT/kkT [k][c]
// tiles, PV-swapped so v stays [c][k]), epilogue split into we-GEMM with
// fused bne stats (recompute in pass2 to fit ws<8.39MB), xT bf16 gather.
#include <hip/hip_runtime.h>

#define B_    8
#define N_    1024
#define K_    32
#define CIN   128
#define COUT  256
#define EPSF  1e-5f
#define NEG   0.2f

// ws layout:
//   float [0..8) M1, [8..72) M2, [72..328) ESUM, [328..584) ESS
//   byte 4096:    wb (65536 shorts: wq,wv,wk2,wv2 bf16)
//   byte 135168:  xT (1048576 shorts: [b*1024+n][128] bf16)
//   byte 2232320: y  (1048576 shorts: [bn][128] bf16)     total 4.33MB
#define WS_M1   0
#define WS_M2   8
#define WS_ESUM 72
#define WS_ESS  328
#define WB_BYTE 4096
#define XT_BYTE 135168
#define Y_BYTE  2232320
#define WQB  0
#define WVB  16384
#define WK2B 32768
#define WV2B 49152

typedef unsigned short ushort_t;
typedef unsigned int   uint_t;
typedef __attribute__((ext_vector_type(8))) short s8v;
typedef __attribute__((ext_vector_type(4))) float f4v;
typedef __bf16 bf16x8 __attribute__((ext_vector_type(8)));

constexpr int   P_TOT  = B_ * N_ * K_;
constexpr float INV_P  = 1.0f / (float)P_TOT;
constexpr float INV_BN = 1.0f / (float)(B_ * N_);

__device__ __forceinline__ float b2f(ushort_t u) {
    return __uint_as_float(((uint_t)u) << 16);
}
__device__ __forceinline__ ushort_t f2b(float f) {
    uint_t u = __float_as_uint(f);
    u += 0x7fffu + ((u >> 16) & 1u);
    return (ushort_t)(u >> 16);
}
__device__ __forceinline__ bf16x8 ld8(const ushort_t* p) {
    return __builtin_bit_cast(bf16x8, *(const s8v*)p);
}
__device__ __forceinline__ bf16x8 pack8(float4 a, float4 b) {
    s8v r;
    r[0] = (short)f2b(a.x); r[1] = (short)f2b(a.y);
    r[2] = (short)f2b(a.z); r[3] = (short)f2b(a.w);
    r[4] = (short)f2b(b.x); r[5] = (short)f2b(b.y);
    r[6] = (short)f2b(b.z); r[7] = (short)f2b(b.w);
    return __builtin_bit_cast(bf16x8, r);
}
// swizzle for s_v [c][32] tiles (R2-proven)
__device__ __forceinline__ int qx(int c, int k) {
    return (c * 32 + k) ^ (((c >> 2) & 3) << 3);
}

// ---------------------------------------------------------------------------
// prep: moments (blk<64) | x transpose->bf16 (64..1087) | weights->bf16 (rest)
// ---------------------------------------------------------------------------
__global__ __launch_bounds__(256) void prep_kernel(
    const float* __restrict__ x, const float* __restrict__ SiPF,
    const float* __restrict__ w_kv, const float* __restrict__ wk2,
    const float* __restrict__ wv2, float* __restrict__ ws,
    ushort_t* __restrict__ wb, ushort_t* __restrict__ xT)
{
    __shared__ float red[4][44];
    __shared__ float tile[32][33];
    const int blk = blockIdx.x;
    const int t   = threadIdx.x;

    if (blk < 64) {                                  // ---- moments of SiPF
        float s1[8], s2[36];
#pragma unroll
        for (int i = 0; i < 8; ++i) s1[i] = 0.f;
#pragma unroll
        for (int i = 0; i < 36; ++i) s2[i] = 0.f;
        const int tid = blk * 256 + t;
        for (int it = 0; it < P_TOT / 16384; ++it) {
            const float4* base = (const float4*)(SiPF + (size_t)(tid + it * 16384) * 8);
            float4 a = base[0], bq = base[1];
            float v[8] = {a.x, a.y, a.z, a.w, bq.x, bq.y, bq.z, bq.w};
            int idx = 0;
#pragma unroll
            for (int i = 0; i < 8; ++i) {
                s1[i] += v[i];
#pragma unroll
                for (int j = i; j < 8; ++j) s2[idx++] += v[i] * v[j];
            }
        }
#pragma unroll
        for (int i = 0; i < 8; ++i)
            for (int m = 32; m; m >>= 1) s1[i] += __shfl_xor(s1[i], m);
#pragma unroll
        for (int i = 0; i < 36; ++i)
            for (int m = 32; m; m >>= 1) s2[i] += __shfl_xor(s2[i], m);
        if ((t & 63) == 0) {
            const int w = t >> 6;
#pragma unroll
            for (int i = 0; i < 8; ++i) red[w][i] = s1[i];
#pragma unroll
            for (int i = 0; i < 36; ++i) red[w][8 + i] = s2[i];
        }
        __syncthreads();
        if (t < 44) {
            const float v = red[0][t] + red[1][t] + red[2][t] + red[3][t];
            if (t < 8) atomicAdd(&ws[WS_M1 + t], v);
            else {
                int p = t - 8, i = 0, row = 8;
                while (p >= row) { p -= row; --row; ++i; }
                const int j = i + p;
                atomicAdd(&ws[WS_M2 + i * 8 + j], v);
                if (i != j) atomicAdd(&ws[WS_M2 + j * 8 + i], v);
            }
        }
    } else if (blk < 1088) {                         // ---- x -> xT bf16
        const int tb  = blk - 64;
        const int b   = tb >> 7;
        const int rem = tb & 127;
        const int c0  = (rem >> 5) << 5;
        const int n0  = (rem & 31) << 5;
        const int nn  = t & 31, c8 = t >> 5;
#pragma unroll
        for (int i = 0; i < 4; ++i) {
            const int cc = c8 + i * 8;
            tile[cc][nn] = x[((size_t)(b * CIN + c0 + cc)) * N_ + n0 + nn];
        }
        __syncthreads();
#pragma unroll
        for (int i = 0; i < 4; ++i) {
            const int nr = c8 + i * 8;
            xT[((size_t)(b * N_ + n0 + nr)) * 128 + c0 + nn] = f2b(tile[nn][nr]);
        }
    } else {                                         // ---- weights -> bf16
        const int base = (blk - 1088) * 256 + t;
#pragma unroll
        for (int i = 0; i < 4; ++i) {
            const int e = base + i * 16384;
            float v;
            if (e < 32768)      v = w_kv[e];
            else if (e < 49152) v = wk2[e - 32768];
            else                v = wv2[e - 49152];
            wb[e] = f2b(v);
        }
    }
}

// ---------------------------------------------------------------------------
// main: one block per (b,n) — gather, hk/hv, 4 MFMA GEMMs, MFMA attention, y
// ---------------------------------------------------------------------------
__global__ __launch_bounds__(256, 3) void main_kernel(
    const float* __restrict__ SiPF,
    const float* __restrict__ wk1,  const float* __restrict__ wv1,
    const float* __restrict__ bnk_gamma, const float* __restrict__ bnk_beta,
    const float* __restrict__ bnv_gamma, const float* __restrict__ bnv_beta,
    const float* __restrict__ bv2,  const int* __restrict__ col,
    const float* __restrict__ ws,   const ushort_t* __restrict__ wb,
    const ushort_t* __restrict__ xT, ushort_t* __restrict__ y)
{
    __shared__ __align__(16) ushort_t s_fsT[4096];   // [k][c]; aliased as P in D
    __shared__ __align__(16) ushort_t s_hkT[4096];   // [k][c]
    __shared__ __align__(16) ushort_t s_hvT[4096];   // [k][c]
    __shared__ __align__(16) ushort_t s_qT [4096];   // [k][c] (scale folded)
    __shared__ __align__(16) ushort_t s_kkT[4096];   // [k][c]
    __shared__ __align__(16) ushort_t s_v  [4096];   // [c][k] via qx()
    __shared__ float s_Ak[CIN], s_Bk[CIN], s_Av[CIN], s_Bv[CIN];

    const int bid = blockIdx.x;
    const int bn  = (bid & 7) * 1024 + (bid >> 3);   // XCD swizzle, bijective
    const int b   = bn >> 10;
    const int t   = threadIdx.x;
    const int k   = t & 31;
    const int cg  = t >> 5;

    // ---- Phase A: sipf row, gather (bf16 from xT), BN-fold coeffs ----
    const float4* sp = (const float4*)(SiPF + (size_t)bn * 256 + k * 8);
    float4 sa = sp[0], sb = sp[1];
    float sip[8] = {sa.x, sa.y, sa.z, sa.w, sb.x, sb.y, sb.z, sb.w};

    const int idxk = col[bn * K_ + k] - b * N_;
    const s8v* xrow = (const s8v*)(xT + ((size_t)(b << 10) + idxk) * 128 + cg * 16);
    const s8v fs0 = xrow[0], fs1 = xrow[1];

    if (t < CIN) {
        const int c = t;
        float m1[8], wkr[8], wvr[8];
#pragma unroll
        for (int s = 0; s < 8; ++s) {
            m1[s]  = ws[WS_M1 + s] * INV_P;
            wkr[s] = wk1[c * 8 + s];
            wvr[s] = wv1[c * 8 + s];
        }
        float mk = 0.f, mv = 0.f;
#pragma unroll
        for (int s = 0; s < 8; ++s) { mk += wkr[s] * m1[s]; mv += wvr[s] * m1[s]; }
        float ek = 0.f, ev = 0.f;
#pragma unroll
        for (int s = 0; s < 8; ++s)
#pragma unroll
            for (int s2 = 0; s2 < 8; ++s2) {
                const float m2 = ws[WS_M2 + s * 8 + s2] * INV_P;
                ek += wkr[s] * wkr[s2] * m2;
                ev += wvr[s] * wvr[s2] * m2;
            }
        const float Ak = bnk_gamma[c] * rsqrtf(ek - mk * mk + EPSF);
        const float Av = bnv_gamma[c] * rsqrtf(ev - mv * mv + EPSF);
        s_Ak[c] = Ak; s_Bk[c] = bnk_beta[c] - mk * Ak;   // bv1 cancels in BN
        s_Av[c] = Av; s_Bv[c] = bnv_beta[c] - mv * Av;
    }
    __syncthreads();

    // fs staging (already bf16) + hk/hv compute -> [k][c] swizzled LDS
    {
        const int base = k * 128 + cg * 16;
        const int sw   = (k & 7) << 3;
        *(s8v*)&s_fsT[(base) ^ sw]     = fs0;
        *(s8v*)&s_fsT[(base + 8) ^ sw] = fs1;
    }
#pragma unroll
    for (int i = 0; i < 16; i += 2) {
        const int c = cg * 16 + i;
        const float4 wkA = *(const float4*)&wk1[c * 8];
        const float4 wkB = *(const float4*)&wk1[c * 8 + 4];
        const float4 wkC = *(const float4*)&wk1[c * 8 + 8];
        const float4 wkD = *(const float4*)&wk1[c * 8 + 12];
        const float4 wvA = *(const float4*)&wv1[c * 8];
        const float4 wvB = *(const float4*)&wv1[c * 8 + 4];
        const float4 wvC = *(const float4*)&wv1[c * 8 + 8];
        const float4 wvD = *(const float4*)&wv1[c * 8 + 12];
        const float ak0 = wkA.x*sip[0]+wkA.y*sip[1]+wkA.z*sip[2]+wkA.w*sip[3]
                        + wkB.x*sip[4]+wkB.y*sip[5]+wkB.z*sip[6]+wkB.w*sip[7];
        const float ak1 = wkC.x*sip[0]+wkC.y*sip[1]+wkC.z*sip[2]+wkC.w*sip[3]
                        + wkD.x*sip[4]+wkD.y*sip[5]+wkD.z*sip[6]+wkD.w*sip[7];
        const float av0 = wvA.x*sip[0]+wvA.y*sip[1]+wvA.z*sip[2]+wvA.w*sip[3]
                        + wvB.x*sip[4]+wvB.y*sip[5]+wvB.z*sip[6]+wvB.w*sip[7];
        const float av1 = wvC.x*sip[0]+wvC.y*sip[1]+wvC.z*sip[2]+wvC.w*sip[3]
                        + wvD.x*sip[4]+wvD.y*sip[5]+wvD.z*sip[6]+wvD.w*sip[7];
        const float hk0 = fmaxf(s_Ak[c] * ak0 + s_Bk[c], 0.f);
        const float hk1 = fmaxf(s_Ak[c+1] * ak1 + s_Bk[c+1], 0.f);
        const float hv0 = fmaxf(s_Av[c] * av0 + s_Bv[c], 0.f);
        const float hv1 = fmaxf(s_Av[c+1] * av1 + s_Bv[c+1], 0.f);
        const int idx = (k * 128 + c) ^ ((k & 7) << 3);
        *(uint_t*)&s_hkT[idx] = (uint_t)f2b(hk0) | ((uint_t)f2b(hk1) << 16);
        *(uint_t*)&s_hvT[idx] = (uint_t)f2b(hv0) | ((uint_t)f2b(hv1) << 16);
    }
    __syncthreads();

    const int wv_ = t >> 6, l = t & 63, lr = l & 15, lg = l >> 4;
    const f4v z4 = {0.f, 0.f, 0.f, 0.f};

    // ---- Phase B: q = Wq@fs (scaled), vfs = Wv@fs ----
    f4v aq[2][2], av[2][2];
#pragma unroll
    for (int mi = 0; mi < 2; ++mi)
#pragma unroll
        for (int ni = 0; ni < 2; ++ni) { aq[mi][ni] = z4; av[mi][ni] = z4; }
#pragma unroll
    for (int kt = 0; kt < 4; ++kt) {
        const int cp0 = kt * 32 + lg * 8;
        bf16x8 bfr[2];
#pragma unroll
        for (int ni = 0; ni < 2; ++ni) {
            const int kk_ = ni * 16 + lr;
            bfr[ni] = ld8(&s_fsT[(kk_ * 128 + cp0) ^ ((lr & 7) << 3)]);
        }
#pragma unroll
        for (int mi = 0; mi < 2; ++mi) {
            const int c = wv_ * 32 + mi * 16 + lr;
            const bf16x8 a1 = ld8(&wb[WQB + c * 128 + cp0]);
            const bf16x8 a2 = ld8(&wb[WVB + c * 128 + cp0]);
#pragma unroll
            for (int ni = 0; ni < 2; ++ni) {
                aq[mi][ni] = __builtin_amdgcn_mfma_f32_16x16x32_bf16(a1, bfr[ni], aq[mi][ni], 0, 0, 0);
                av[mi][ni] = __builtin_amdgcn_mfma_f32_16x16x32_bf16(a2, bfr[ni], av[mi][ni], 0, 0, 0);
            }
        }
    }
    const float SC = 0.17677669529663687f;           // 1/sqrt(32)
#pragma unroll
    for (int mi = 0; mi < 2; ++mi)
#pragma unroll
        for (int ni = 0; ni < 2; ++ni)
#pragma unroll
            for (int r = 0; r < 4; ++r) {
                const int c   = wv_ * 32 + mi * 16 + lg * 4 + r;
                const int kk_ = ni * 16 + lr;
                s_qT[(kk_ * 128 + c) ^ ((lr & 7) << 3)] = f2b(aq[mi][ni][r] * SC);
            }

    // ---- Phase C: kk = wk2@hk, v = vfs*(wv2@hv + bv2) ----
    f4v ck[2][2], cs[2][2];
#pragma unroll
    for (int mi = 0; mi < 2; ++mi)
#pragma unroll
        for (int ni = 0; ni < 2; ++ni) { ck[mi][ni] = z4; cs[mi][ni] = z4; }
#pragma unroll
    for (int kt = 0; kt < 4; ++kt) {
        const int cp0 = kt * 32 + lg * 8;
        bf16x8 bk[2], bv[2];
#pragma unroll
        for (int ni = 0; ni < 2; ++ni) {
            const int kk_ = ni * 16 + lr;
            const int idx = (kk_ * 128 + cp0) ^ ((lr & 7) << 3);
            bk[ni] = ld8(&s_hkT[idx]);
            bv[ni] = ld8(&s_hvT[idx]);
        }
#pragma unroll
        for (int mi = 0; mi < 2; ++mi) {
            const int c = wv_ * 32 + mi * 16 + lr;
            const bf16x8 a1 = ld8(&wb[WK2B + c * 128 + cp0]);
            const bf16x8 a2 = ld8(&wb[WV2B + c * 128 + cp0]);
#pragma unroll
            for (int ni = 0; ni < 2; ++ni) {
                ck[mi][ni] = __builtin_amdgcn_mfma_f32_16x16x32_bf16(a1, bk[ni], ck[mi][ni], 0, 0, 0);
                cs[mi][ni] = __builtin_amdgcn_mfma_f32_16x16x32_bf16(a2, bv[ni], cs[mi][ni], 0, 0, 0);
            }
        }
    }
#pragma unroll
    for (int mi = 0; mi < 2; ++mi)
#pragma unroll
        for (int ni = 0; ni < 2; ++ni)
#pragma unroll
            for (int r = 0; r < 4; ++r) {
                const int c   = wv_ * 32 + mi * 16 + lg * 4 + r;
                const int kk_ = ni * 16 + lr;
                s_kkT[(kk_ * 128 + c) ^ ((lr & 7) << 3)] = f2b(ck[mi][ni][r]);
                s_v[qx(c, kk_)] = f2b(av[mi][ni][r] * (cs[mi][ni][r] + bv2[c]));
            }
    __syncthreads();   // fsT dead (last read phase B) -> safe to alias as P

    // ---- Phase D: attention, head = wave ----
    {
        const int h = wv_;
        bf16x8 aqf[2], bkf[2];
#pragma unroll
        for (int mt = 0; mt < 2; ++mt)
            aqf[mt] = ld8(&s_qT[((mt * 16 + lr) * 128 + h * 32 + lg * 8) ^ ((lr & 7) << 3)]);
#pragma unroll
        for (int nt = 0; nt < 2; ++nt)
            bkf[nt] = ld8(&s_kkT[((nt * 16 + lr) * 128 + h * 32 + lg * 8) ^ ((lr & 7) << 3)]);
        f4v s[2][2];
#pragma unroll
        for (int mt = 0; mt < 2; ++mt)
#pragma unroll
            for (int nt = 0; nt < 2; ++nt)
                s[mt][nt] = __builtin_amdgcn_mfma_f32_16x16x32_bf16(aqf[mt], bkf[nt], z4, 0, 0, 0);

        float rm[2][4], rs[2][4];
#pragma unroll
        for (int mt = 0; mt < 2; ++mt)
#pragma unroll
            for (int r = 0; r < 4; ++r)
                rm[mt][r] = fmaxf(s[mt][0][r], s[mt][1][r]);
#pragma unroll
        for (int m = 1; m <= 8; m <<= 1)
#pragma unroll
            for (int mt = 0; mt < 2; ++mt)
#pragma unroll
                for (int r = 0; r < 4; ++r)
                    rm[mt][r] = fmaxf(rm[mt][r], __shfl_xor(rm[mt][r], m));
#pragma unroll
        for (int mt = 0; mt < 2; ++mt)
#pragma unroll
            for (int nt = 0; nt < 2; ++nt)
#pragma unroll
                for (int r = 0; r < 4; ++r)
                    s[mt][nt][r] = __expf(s[mt][nt][r] - rm[mt][r]);
#pragma unroll
        for (int mt = 0; mt < 2; ++mt)
#pragma unroll
            for (int r = 0; r < 4; ++r)
                rs[mt][r] = s[mt][0][r] + s[mt][1][r];
#pragma unroll
        for (int m = 1; m <= 8; m <<= 1)
#pragma unroll
            for (int mt = 0; mt < 2; ++mt)
#pragma unroll
                for (int r = 0; r < 4; ++r)
                    rs[mt][r] += __shfl_xor(rs[mt][r], m);
#pragma unroll
        for (int mt = 0; mt < 2; ++mt)
#pragma unroll
            for (int r = 0; r < 4; ++r)
                rs[mt][r] = 1.0f / rs[mt][r];

        ushort_t* P = s_fsT + h * 1024;              // [kq][j] swizzled
#pragma unroll
        for (int mt = 0; mt < 2; ++mt)
#pragma unroll
            for (int nt = 0; nt < 2; ++nt)
#pragma unroll
                for (int r = 0; r < 4; ++r) {
                    const int kq = mt * 16 + lg * 4 + r;
                    const int j  = nt * 16 + lr;
                    P[(kq * 32 + j) ^ ((kq & 7) << 3)] = f2b(s[mt][nt][r] * rs[mt][r]);
                }

        bf16x8 af[2], pb[2];
#pragma unroll
        for (int mt2 = 0; mt2 < 2; ++mt2)
            af[mt2] = ld8(&s_v[qx(h * 32 + mt2 * 16 + lr, lg * 8)]);
#pragma unroll
        for (int nt2 = 0; nt2 < 2; ++nt2) {
            const int kq2 = nt2 * 16 + lr;
            pb[nt2] = ld8(&P[(kq2 * 32 + lg * 8) ^ ((lr & 7) << 3)]);
        }
        f4v o2[2][2];
#pragma unroll
        for (int mt2 = 0; mt2 < 2; ++mt2)
#pragma unroll
            for (int nt2 = 0; nt2 < 2; ++nt2)
                o2[mt2][nt2] = __builtin_amdgcn_mfma_f32_16x16x32_bf16(af[mt2], pb[nt2], z4, 0, 0, 0);

        float ym[2][4];
#pragma unroll
        for (int mt2 = 0; mt2 < 2; ++mt2)
#pragma unroll
            for (int r = 0; r < 4; ++r)
                ym[mt2][r] = fmaxf(o2[mt2][0][r], o2[mt2][1][r]);
#pragma unroll
        for (int m = 1; m <= 8; m <<= 1)
#pragma unroll
            for (int mt2 = 0; mt2 < 2; ++mt2)
#pragma unroll
                for (int r = 0; r < 4; ++r)
                    ym[mt2][r] = fmaxf(ym[mt2][r], __shfl_xor(ym[mt2][r], m));
        if (lr == 0) {
#pragma unroll
            for (int mt2 = 0; mt2 < 2; ++mt2) {
                unsigned long long pk = 0;
#pragma unroll
                for (int r = 0; r < 4; ++r)
                    pk |= ((unsigned long long)f2b(ym[mt2][r])) << (16 * r);
                *(unsigned long long*)&y[(size_t)bn * 128 + h * 32 + mt2 * 16 + lg * 4] = pk;
            }
        }
    }
}

// ---------------------------------------------------------------------------
// zgemm: z = we @ cat(y-x, x). MODE 0: accumulate bne stats (atomics).
//        MODE 1: recompute z, normalize + leaky, write out.
// ---------------------------------------------------------------------------
template <int MODE>
__global__ __launch_bounds__(256) void zgemm_kernel(
    const float* __restrict__ we, const ushort_t* __restrict__ xT,
    const ushort_t* __restrict__ y, float* __restrict__ ws,
    const float* __restrict__ gamma, const float* __restrict__ beta,
    float* __restrict__ out)
{
    __shared__ __align__(16) ushort_t Bt[32 * 256];  // [bn-local][c] swizzled
    const int blk = blockIdx.x;                      // 256 blocks
    const int bn0 = blk * 32;
    const int t   = threadIdx.x;
    {
        const int r   = t >> 3;
        const int c0  = (t & 7) * 16;
        const int bnr = bn0 + r;
        const s8v* yr = (const s8v*)(y  + (size_t)bnr * 128 + c0);
        const s8v* xr = (const s8v*)(xT + (size_t)bnr * 128 + c0);
        const s8v y0 = yr[0], y1 = yr[1], x0 = xr[0], x1 = xr[1];
        s8v d0, d1;
#pragma unroll
        for (int j = 0; j < 8; ++j) {
            d0[j] = (short)f2b(b2f((ushort_t)y0[j]) - b2f((ushort_t)x0[j]));
            d1[j] = (short)f2b(b2f((ushort_t)y1[j]) - b2f((ushort_t)x1[j]));
        }
        const int sw = (r & 7) << 3;
        *(s8v*)&Bt[(r * 256 + c0) ^ sw]       = d0;
        *(s8v*)&Bt[(r * 256 + c0 + 8) ^ sw]   = d1;
        *(s8v*)&Bt[(r * 256 + 128 + c0) ^ sw]     = x0;
        *(s8v*)&Bt[(r * 256 + 128 + c0 + 8) ^ sw] = x1;
    }
    __syncthreads();

    const int w = t >> 6, l = t & 63, lr = l & 15, lg = l >> 4;
    const f4v z4 = {0.f, 0.f, 0.f, 0.f};
    f4v acc[4][2];
#pragma unroll
    for (int mt = 0; mt < 4; ++mt)
#pragma unroll
        for (int nt = 0; nt < 2; ++nt) acc[mt][nt] = z4;

#pragma unroll
    for (int kt = 0; kt < 8; ++kt) {
        const int kc = kt * 32 + lg * 8;
        bf16x8 bf[2];
#pragma unroll
        for (int nt = 0; nt < 2; ++nt) {
            const int rl = nt * 16 + lr;
            bf[nt] = ld8(&Bt[(rl * 256 + kc) ^ ((lr & 7) << 3)]);
        }
#pragma unroll
        for (int mt = 0; mt < 4; ++mt) {
            const int o = w * 64 + mt * 16 + lr;
            const float4 wa = *(const float4*)&we[(size_t)o * 256 + kc];
            const float4 wbq = *(const float4*)&we[(size_t)o * 256 + kc + 4];
            const bf16x8 am = pack8(wa, wbq);
#pragma unroll
            for (int nt = 0; nt < 2; ++nt)
                acc[mt][nt] = __builtin_amdgcn_mfma_f32_16x16x32_bf16(am, bf[nt], acc[mt][nt], 0, 0, 0);
        }
    }

    if (MODE == 0) {
        float sm[4][4], sq[4][4];
#pragma unroll
        for (int mt = 0; mt < 4; ++mt)
#pragma unroll
            for (int r = 0; r < 4; ++r) {
                const float a0 = acc[mt][0][r], a1 = acc[mt][1][r];
                sm[mt][r] = a0 + a1;
                sq[mt][r] = a0 * a0 + a1 * a1;
            }
#pragma unroll
        for (int m = 1; m <= 8; m <<= 1)
#pragma unroll
            for (int mt = 0; mt < 4; ++mt)
#pragma unroll
                for (int r = 0; r < 4; ++r) {
                    sm[mt][r] += __shfl_xor(sm[mt][r], m);
                    sq[mt][r] += __shfl_xor(sq[mt][r], m);
                }
        if (lr == 0) {
#pragma unroll
            for (int mt = 0; mt < 4; ++mt)
#pragma unroll
                for (int r = 0; r < 4; ++r) {
                    const int o = w * 64 + mt * 16 + lg * 4 + r;
                    atomicAdd(&ws[WS_ESUM + o], sm[mt][r]);
                    atomicAdd(&ws[WS_ESS + o],  sq[mt][r]);
                }
        }
    } else {
        const int b = bn0 >> 10;
#pragma unroll
        for (int mt = 0; mt < 4; ++mt)
#pragma unroll
            for (int r = 0; r < 4; ++r) {
                const int o = w * 64 + mt * 16 + lg * 4 + r;
                const float mean = ws[WS_ESUM + o] * INV_BN;
                const float var  = ws[WS_ESS + o] * INV_BN - mean * mean;
                const float A  = gamma[o] * rsqrtf(var + EPSF);
                const float Bb = beta[o] - mean * A;
#pragma unroll
                for (int nt = 0; nt < 2; ++nt) {
                    const int n  = (bn0 + nt * 16 + lr) & (N_ - 1);
                    const float rv = A * acc[mt][nt][r] + Bb;
                    out[((size_t)(b * COUT + o)) * N_ + n] = rv >= 0.f ? rv : NEG * rv;
                }
            }
    }
}

// ---------------------------------------------------------------------------
extern "C" void kernel_launch(void* const* d_in, const int* in_sizes, int n_in,
                              void* d_out, int out_size, void* d_ws, size_t ws_size,
                              hipStream_t stream)
{
    (void)in_sizes; (void)n_in; (void)out_size; (void)ws_size;

    const float* x         = (const float*)d_in[0];
    const float* SiPF      = (const float*)d_in[1];
    const float* w_kv      = (const float*)d_in[2];
    const float* wk1       = (const float*)d_in[3];
    const float* bnk_gamma = (const float*)d_in[4];
    const float* bnk_beta  = (const float*)d_in[5];
    const float* wk2       = (const float*)d_in[6];
    const float* wv1       = (const float*)d_in[7];
    // d_in[8] = bv1: cancels inside _bn2d — unused
    const float* bnv_gamma = (const float*)d_in[9];
    const float* bnv_beta  = (const float*)d_in[10];
    const float* wv2       = (const float*)d_in[11];
    const float* bv2       = (const float*)d_in[12];
    const float* we        = (const float*)d_in[13];
    const float* bne_gamma = (const float*)d_in[14];
    const float* bne_beta  = (const float*)d_in[15];
    const int*   col       = (const int*)d_in[16];

    float*    ws = (float*)d_ws;
    ushort_t* wb = (ushort_t*)((char*)d_ws + WB_BYTE);
    ushort_t* xT = (ushort_t*)((char*)d_ws + XT_BYTE);
    ushort_t* y  = (ushort_t*)((char*)d_ws + Y_BYTE);

    hipMemsetAsync(d_ws, 0, 584 * sizeof(float), stream);

    prep_kernel<<<1152, 256, 0, stream>>>(x, SiPF, w_kv, wk2, wv2, ws, wb, xT);
    main_kernel<<<8192, 256, 0, stream>>>(
        SiPF, wk1, wv1, bnk_gamma, bnk_beta, bnv_gamma, bnv_beta,
        bv2, col, ws, wb, xT, y);
    zgemm_kernel<0><<<256, 256, 0, stream>>>(we, xT, y, ws, bne_gamma, bne_beta,
                                             (float*)d_out);
    zgemm_kernel<1><<<256, 256, 0, stream>>>(we, xT, y, ws, bne_gamma, bne_beta,
                                             (float*)d_out);
}

// Round 4
// 253.416 us; speedup vs baseline: 14.8447x; 1.2322x over previous
//
// RINet fused — R4: hoisted BN-fold, MFMA hk/hv, cvt-cast f2b, 4 blk/CU
// Journal: R1 3762us fp32-VALU. R2 505us (MFMA GEMMs; attn VALU + scratch).
// R3 312us (MFMA attn + zgemm; main 229us, VALUBusy 40%, MfmaUtil 7%, occ 33%).
// R4: (1) BN-fold coeffs computed once in prep2 (was per-block x8192),
// Ak-folded zero-padded bf16 wk1/wv1 -> hk/hv via MFMA; (2) f2b via __bf16
// cast (v_cvt_pk_bf16_f32) not 3-op manual RNE; (3) phase order A,hkhv,C,B,D
// aliases qT->hkT, v->hvT: LDS 50->36KB = 4 blk/CU; (4) we prepped to bf16.
#include <hip/hip_runtime.h>

#define B_    8
#define N_    1024
#define K_    32
#define CIN   128
#define COUT  256
#define EPSF  1e-5f
#define NEG   0.2f

// ws float offsets
#define WS_M1   0
#define WS_M2   8
#define WS_ESUM 72
#define WS_ESS  328
#define WS_BK   584
#define WS_BV   712
// ws byte offsets
#define WB_BYTE 4096
#define XT_BYTE 282624     // 4096 + 139264*2
#define Y_BYTE  2379776    // XT + 2MB    (total 4.27MB)
// short offsets inside wb
#define WQB   0
#define WVB   16384
#define WK2B  32768
#define WV2B  49152
#define WEB   65536
#define WK1F  131072
#define WV1F  135168

typedef unsigned short ushort_t;
typedef unsigned int   uint_t;
typedef __attribute__((ext_vector_type(8))) short s8v;
typedef __attribute__((ext_vector_type(4))) float f4v;
typedef __bf16 bf16x8 __attribute__((ext_vector_type(8)));

constexpr int   P_TOT  = B_ * N_ * K_;
constexpr float INV_P  = 1.0f / (float)P_TOT;
constexpr float INV_BN = 1.0f / (float)(B_ * N_);

__device__ __forceinline__ float b2f(ushort_t u) {
    return __uint_as_float(((uint_t)u) << 16);
}
__device__ __forceinline__ ushort_t f2b(float f) {      // v_cvt_pk_bf16_f32
    return __builtin_bit_cast(ushort_t, (__bf16)f);
}
__device__ __forceinline__ bf16x8 ld8(const ushort_t* p) {
    return __builtin_bit_cast(bf16x8, *(const s8v*)p);
}
__device__ __forceinline__ int qx(int c, int k) {       // [c][32] v-tile swz
    return (c * 32 + k) ^ (((c >> 2) & 3) << 3);
}

// ---------------------------------------------------------------------------
// prep: moments (blk<64) | xT bf16 (64..1087) | weights bf16 (1088..1215)
// ---------------------------------------------------------------------------
__global__ __launch_bounds__(256) void prep_kernel(
    const float* __restrict__ x, const float* __restrict__ SiPF,
    const float* __restrict__ w_kv, const float* __restrict__ wk2,
    const float* __restrict__ wv2, const float* __restrict__ we,
    float* __restrict__ ws, ushort_t* __restrict__ wb,
    ushort_t* __restrict__ xT)
{
    __shared__ float red[4][44];
    __shared__ float tile[32][33];
    const int blk = blockIdx.x;
    const int t   = threadIdx.x;

    if (blk < 64) {                                  // ---- moments of SiPF
        float s1[8], s2[36];
#pragma unroll
        for (int i = 0; i < 8; ++i) s1[i] = 0.f;
#pragma unroll
        for (int i = 0; i < 36; ++i) s2[i] = 0.f;
        const int tid = blk * 256 + t;
        for (int it = 0; it < P_TOT / 16384; ++it) {
            const float4* base = (const float4*)(SiPF + (size_t)(tid + it * 16384) * 8);
            float4 a = base[0], bq = base[1];
            float v[8] = {a.x, a.y, a.z, a.w, bq.x, bq.y, bq.z, bq.w};
            int idx = 0;
#pragma unroll
            for (int i = 0; i < 8; ++i) {
                s1[i] += v[i];
#pragma unroll
                for (int j = i; j < 8; ++j) s2[idx++] += v[i] * v[j];
            }
        }
#pragma unroll
        for (int i = 0; i < 8; ++i)
            for (int m = 32; m; m >>= 1) s1[i] += __shfl_xor(s1[i], m);
#pragma unroll
        for (int i = 0; i < 36; ++i)
            for (int m = 32; m; m >>= 1) s2[i] += __shfl_xor(s2[i], m);
        if ((t & 63) == 0) {
            const int w = t >> 6;
#pragma unroll
            for (int i = 0; i < 8; ++i) red[w][i] = s1[i];
#pragma unroll
            for (int i = 0; i < 36; ++i) red[w][8 + i] = s2[i];
        }
        __syncthreads();
        if (t < 44) {
            const float v = red[0][t] + red[1][t] + red[2][t] + red[3][t];
            if (t < 8) atomicAdd(&ws[WS_M1 + t], v);
            else {
                int p = t - 8, i = 0, row = 8;
                while (p >= row) { p -= row; --row; ++i; }
                const int j = i + p;
                atomicAdd(&ws[WS_M2 + i * 8 + j], v);
                if (i != j) atomicAdd(&ws[WS_M2 + j * 8 + i], v);
            }
        }
    } else if (blk < 1088) {                         // ---- x -> xT bf16
        const int tb  = blk - 64;
        const int b   = tb >> 7;
        const int rem = tb & 127;
        const int c0  = (rem >> 5) << 5;
        const int n0  = (rem & 31) << 5;
        const int nn  = t & 31, c8 = t >> 5;
#pragma unroll
        for (int i = 0; i < 4; ++i) {
            const int cc = c8 + i * 8;
            tile[cc][nn] = x[((size_t)(b * CIN + c0 + cc)) * N_ + n0 + nn];
        }
        __syncthreads();
#pragma unroll
        for (int i = 0; i < 4; ++i) {
            const int nr = c8 + i * 8;
            xT[((size_t)(b * N_ + n0 + nr)) * 128 + c0 + nn] = f2b(tile[nn][nr]);
        }
    } else {                                         // ---- weights -> bf16
        const int base = (blk - 1088) * 1024 + t;
#pragma unroll
        for (int i = 0; i < 4; ++i) {
            const int e = base + i * 256;
            float v;
            if (e < 32768)      v = w_kv[e];
            else if (e < 49152) v = wk2[e - 32768];
            else if (e < 65536) v = wv2[e - 49152];
            else                v = we[e - 65536];
            wb[e] = f2b(v);
        }
    }
}

// ---------------------------------------------------------------------------
// prep2: BN-fold coeffs (once) + Ak-folded zero-padded bf16 wk1/wv1
// ---------------------------------------------------------------------------
__global__ __launch_bounds__(128) void prep2_kernel(
    const float* __restrict__ wk1, const float* __restrict__ wv1,
    const float* __restrict__ bnk_gamma, const float* __restrict__ bnk_beta,
    const float* __restrict__ bnv_gamma, const float* __restrict__ bnv_beta,
    float* __restrict__ ws, ushort_t* __restrict__ wb)
{
    const int c = threadIdx.x;
    float m1[8], wkr[8], wvr[8];
#pragma unroll
    for (int s = 0; s < 8; ++s) {
        m1[s]  = ws[WS_M1 + s] * INV_P;
        wkr[s] = wk1[c * 8 + s];
        wvr[s] = wv1[c * 8 + s];
    }
    float mk = 0.f, mv = 0.f;
#pragma unroll
    for (int s = 0; s < 8; ++s) { mk += wkr[s] * m1[s]; mv += wvr[s] * m1[s]; }
    float ek = 0.f, ev = 0.f;
#pragma unroll
    for (int s = 0; s < 8; ++s)
#pragma unroll
        for (int s2 = 0; s2 < 8; ++s2) {
            const float m2 = ws[WS_M2 + s * 8 + s2] * INV_P;
            ek += wkr[s] * wkr[s2] * m2;
            ev += wvr[s] * wvr[s2] * m2;
        }
    const float Ak = bnk_gamma[c] * rsqrtf(ek - mk * mk + EPSF);
    const float Av = bnv_gamma[c] * rsqrtf(ev - mv * mv + EPSF);
    ws[WS_BK + c] = bnk_beta[c] - mk * Ak;           // bv1 cancels in BN
    ws[WS_BV + c] = bnv_beta[c] - mv * Av;
#pragma unroll
    for (int s = 0; s < 32; ++s) {
        wb[WK1F + c * 32 + s] = s < 8 ? f2b(Ak * wkr[s]) : (ushort_t)0;
        wb[WV1F + c * 32 + s] = s < 8 ? f2b(Av * wvr[s]) : (ushort_t)0;
    }
}

// ---------------------------------------------------------------------------
// main: one block per (b,n). Phases: A stage | hk/hv MFMA | C | B | D attn
// ---------------------------------------------------------------------------
__global__ __launch_bounds__(256, 4) void main_kernel(
    const float* __restrict__ SiPF, const float* __restrict__ bv2,
    const int* __restrict__ col,    const float* __restrict__ ws,
    const ushort_t* __restrict__ wb, const ushort_t* __restrict__ xT,
    ushort_t* __restrict__ y)
{
    __shared__ __align__(16) ushort_t T1[4096];      // fsT [k][c]; then P
    __shared__ __align__(16) ushort_t T2[4096];      // hkT [k][c]; then qT
    __shared__ __align__(16) ushort_t T3[4096];      // hvT [k][c]; then v [c][k]
    __shared__ __align__(16) ushort_t T4[4096];      // kkT [k][c]
    __shared__ __align__(16) ushort_t s_sipf[1024];  // [k][32] swz, K-padded
    __shared__ float s_Bk[CIN], s_Bv[CIN], s_bv2[CIN];

    const int bid = blockIdx.x;
    const int bn  = (bid & 7) * 1024 + (bid >> 3);   // XCD swizzle, bijective
    const int b   = bn >> 10;
    const int t   = threadIdx.x;
    const int k   = t & 31;
    const int cg  = t >> 5;

    // ---- Phase A: stage sipf (bf16, K-pad), gather fs, coeff loads ----
    if (cg < 4) {
        const int slot = (cg * 8) ^ ((k & 3) << 3);
        s8v o8 = {0, 0, 0, 0, 0, 0, 0, 0};
        if (cg == 0) {
            const float4* sp = (const float4*)(SiPF + (size_t)bn * 256 + k * 8);
            const float4 sa = sp[0], sq = sp[1];
            o8[0] = (short)f2b(sa.x); o8[1] = (short)f2b(sa.y);
            o8[2] = (short)f2b(sa.z); o8[3] = (short)f2b(sa.w);
            o8[4] = (short)f2b(sq.x); o8[5] = (short)f2b(sq.y);
            o8[6] = (short)f2b(sq.z); o8[7] = (short)f2b(sq.w);
        }
        *(s8v*)&s_sipf[k * 32 + slot] = o8;
    }
    {
        const int idxk = col[bn * K_ + k] - b * N_;
        const s8v* xrow = (const s8v*)(xT + ((size_t)(b << 10) + idxk) * 128 + cg * 16);
        const int base = k * 128 + cg * 16;
        const int sw   = (k & 7) << 3;
        *(s8v*)&T1[(base) ^ sw]     = xrow[0];
        *(s8v*)&T1[(base + 8) ^ sw] = xrow[1];
    }
    if (t < CIN) {
        s_Bk[t]  = ws[WS_BK + t];
        s_Bv[t]  = ws[WS_BV + t];
        s_bv2[t] = bv2[t];
    }
    __syncthreads();

    const int wv_ = t >> 6, l = t & 63, lr = l & 15, lg = l >> 4;
    const f4v z4 = {0.f, 0.f, 0.f, 0.f};

    // ---- Phase A2: hk = relu(wk1f@sipf + Bk), hv likewise (MFMA) ----
    {
        bf16x8 sb[2];
#pragma unroll
        for (int nt = 0; nt < 2; ++nt) {
            const int row = nt * 16 + lr;
            sb[nt] = ld8(&s_sipf[row * 32 + ((lg * 8) ^ ((row & 3) << 3))]);
        }
        f4v hka[2][2], hva[2][2];
#pragma unroll
        for (int mi = 0; mi < 2; ++mi) {
            const int c = wv_ * 32 + mi * 16 + lr;
            const bf16x8 a1 = ld8(&wb[WK1F + c * 32 + lg * 8]);
            const bf16x8 a2 = ld8(&wb[WV1F + c * 32 + lg * 8]);
#pragma unroll
            for (int nt = 0; nt < 2; ++nt) {
                hka[mi][nt] = __builtin_amdgcn_mfma_f32_16x16x32_bf16(a1, sb[nt], z4, 0, 0, 0);
                hva[mi][nt] = __builtin_amdgcn_mfma_f32_16x16x32_bf16(a2, sb[nt], z4, 0, 0, 0);
            }
        }
#pragma unroll
        for (int mi = 0; mi < 2; ++mi)
#pragma unroll
            for (int nt = 0; nt < 2; ++nt)
#pragma unroll
                for (int r = 0; r < 4; ++r) {
                    const int c  = wv_ * 32 + mi * 16 + lg * 4 + r;
                    const int kc = nt * 16 + lr;
                    const int idx = (kc * 128 + c) ^ ((kc & 7) << 3);
                    T2[idx] = f2b(fmaxf(hka[mi][nt][r] + s_Bk[c], 0.f));
                    T3[idx] = f2b(fmaxf(hva[mi][nt][r] + s_Bv[c], 0.f));
                }
    }
    __syncthreads();

    // ---- Phase C: kk = wk2@hk -> T4; cs = wv2@hv held in regs ----
    f4v ck[2][2], cs[2][2];
#pragma unroll
    for (int mi = 0; mi < 2; ++mi)
#pragma unroll
        for (int ni = 0; ni < 2; ++ni) { ck[mi][ni] = z4; cs[mi][ni] = z4; }
#pragma unroll
    for (int kt = 0; kt < 4; ++kt) {
        const int cp0 = kt * 32 + lg * 8;
        bf16x8 bk[2], bv[2];
#pragma unroll
        for (int ni = 0; ni < 2; ++ni) {
            const int kk_ = ni * 16 + lr;
            const int idx = (kk_ * 128 + cp0) ^ ((lr & 7) << 3);
            bk[ni] = ld8(&T2[idx]);
            bv[ni] = ld8(&T3[idx]);
        }
#pragma unroll
        for (int mi = 0; mi < 2; ++mi) {
            const int c = wv_ * 32 + mi * 16 + lr;
            const bf16x8 a1 = ld8(&wb[WK2B + c * 128 + cp0]);
            const bf16x8 a2 = ld8(&wb[WV2B + c * 128 + cp0]);
#pragma unroll
            for (int ni = 0; ni < 2; ++ni) {
                ck[mi][ni] = __builtin_amdgcn_mfma_f32_16x16x32_bf16(a1, bk[ni], ck[mi][ni], 0, 0, 0);
                cs[mi][ni] = __builtin_amdgcn_mfma_f32_16x16x32_bf16(a2, bv[ni], cs[mi][ni], 0, 0, 0);
            }
        }
    }
#pragma unroll
    for (int mi = 0; mi < 2; ++mi)
#pragma unroll
        for (int ni = 0; ni < 2; ++ni)
#pragma unroll
            for (int r = 0; r < 4; ++r) {
                const int c   = wv_ * 32 + mi * 16 + lg * 4 + r;
                const int kk_ = ni * 16 + lr;
                T4[(kk_ * 128 + c) ^ ((kk_ & 7) << 3)] = f2b(ck[mi][ni][r]);
            }
    __syncthreads();   // all waves done reading T2/T3 -> safe to overwrite

    // ---- Phase B: q = Wq@fs (scaled) -> T2; v = vfs*(cs+bv2) -> T3 ----
    {
        f4v aq[2][2], av[2][2];
#pragma unroll
        for (int mi = 0; mi < 2; ++mi)
#pragma unroll
            for (int ni = 0; ni < 2; ++ni) { aq[mi][ni] = z4; av[mi][ni] = z4; }
#pragma unroll
        for (int kt = 0; kt < 4; ++kt) {
            const int cp0 = kt * 32 + lg * 8;
            bf16x8 bfr[2];
#pragma unroll
            for (int ni = 0; ni < 2; ++ni) {
                const int kk_ = ni * 16 + lr;
                bfr[ni] = ld8(&T1[(kk_ * 128 + cp0) ^ ((lr & 7) << 3)]);
            }
#pragma unroll
            for (int mi = 0; mi < 2; ++mi) {
                const int c = wv_ * 32 + mi * 16 + lr;
                const bf16x8 a1 = ld8(&wb[WQB + c * 128 + cp0]);
                const bf16x8 a2 = ld8(&wb[WVB + c * 128 + cp0]);
#pragma unroll
                for (int ni = 0; ni < 2; ++ni) {
                    aq[mi][ni] = __builtin_amdgcn_mfma_f32_16x16x32_bf16(a1, bfr[ni], aq[mi][ni], 0, 0, 0);
                    av[mi][ni] = __builtin_amdgcn_mfma_f32_16x16x32_bf16(a2, bfr[ni], av[mi][ni], 0, 0, 0);
                }
            }
        }
        const float SC = 0.17677669529663687f;       // 1/sqrt(32)
#pragma unroll
        for (int mi = 0; mi < 2; ++mi)
#pragma unroll
            for (int ni = 0; ni < 2; ++ni)
#pragma unroll
                for (int r = 0; r < 4; ++r) {
                    const int c   = wv_ * 32 + mi * 16 + lg * 4 + r;
                    const int kk_ = ni * 16 + lr;
                    T2[(kk_ * 128 + c) ^ ((kk_ & 7) << 3)] = f2b(aq[mi][ni][r] * SC);
                    T3[qx(c, kk_)] = f2b(av[mi][ni][r] * (cs[mi][ni][r] + s_bv2[c]));
                }
    }
    __syncthreads();   // T1 reads done -> P may alias it

    // ---- Phase D: attention, head = wave ----
    {
        const int h = wv_;
        bf16x8 aqf[2], bkf[2];
#pragma unroll
        for (int mt = 0; mt < 2; ++mt)
            aqf[mt] = ld8(&T2[((mt * 16 + lr) * 128 + h * 32 + lg * 8) ^ ((lr & 7) << 3)]);
#pragma unroll
        for (int nt = 0; nt < 2; ++nt)
            bkf[nt] = ld8(&T4[((nt * 16 + lr) * 128 + h * 32 + lg * 8) ^ ((lr & 7) << 3)]);
        f4v s[2][2];
#pragma unroll
        for (int mt = 0; mt < 2; ++mt)
#pragma unroll
            for (int nt = 0; nt < 2; ++nt)
                s[mt][nt] = __builtin_amdgcn_mfma_f32_16x16x32_bf16(aqf[mt], bkf[nt], z4, 0, 0, 0);

        float rm[2][4], rs[2][4];
#pragma unroll
        for (int mt = 0; mt < 2; ++mt)
#pragma unroll
            for (int r = 0; r < 4; ++r)
                rm[mt][r] = fmaxf(s[mt][0][r], s[mt][1][r]);
#pragma unroll
        for (int m = 1; m <= 8; m <<= 1)
#pragma unroll
            for (int mt = 0; mt < 2; ++mt)
#pragma unroll
                for (int r = 0; r < 4; ++r)
                    rm[mt][r] = fmaxf(rm[mt][r], __shfl_xor(rm[mt][r], m));
#pragma unroll
        for (int mt = 0; mt < 2; ++mt)
#pragma unroll
            for (int nt = 0; nt < 2; ++nt)
#pragma unroll
                for (int r = 0; r < 4; ++r)
                    s[mt][nt][r] = __expf(s[mt][nt][r] - rm[mt][r]);
#pragma unroll
        for (int mt = 0; mt < 2; ++mt)
#pragma unroll
            for (int r = 0; r < 4; ++r)
                rs[mt][r] = s[mt][0][r] + s[mt][1][r];
#pragma unroll
        for (int m = 1; m <= 8; m <<= 1)
#pragma unroll
            for (int mt = 0; mt < 2; ++mt)
#pragma unroll
                for (int r = 0; r < 4; ++r)
                    rs[mt][r] += __shfl_xor(rs[mt][r], m);
#pragma unroll
        for (int mt = 0; mt < 2; ++mt)
#pragma unroll
            for (int r = 0; r < 4; ++r)
                rs[mt][r] = 1.0f / rs[mt][r];

        ushort_t* P = T1 + h * 1024;                 // [kq][j] swizzled
#pragma unroll
        for (int mt = 0; mt < 2; ++mt)
#pragma unroll
            for (int nt = 0; nt < 2; ++nt)
#pragma unroll
                for (int r = 0; r < 4; ++r) {
                    const int kq = mt * 16 + lg * 4 + r;
                    const int j  = nt * 16 + lr;
                    P[(kq * 32 + j) ^ ((kq & 7) << 3)] = f2b(s[mt][nt][r] * rs[mt][r]);
                }

        bf16x8 af[2], pb[2];
#pragma unroll
        for (int mt2 = 0; mt2 < 2; ++mt2)
            af[mt2] = ld8(&T3[qx(h * 32 + mt2 * 16 + lr, lg * 8)]);
#pragma unroll
        for (int nt2 = 0; nt2 < 2; ++nt2) {
            const int kq2 = nt2 * 16 + lr;
            pb[nt2] = ld8(&P[(kq2 * 32 + lg * 8) ^ ((lr & 7) << 3)]);
        }
        f4v o2[2][2];
#pragma unroll
        for (int mt2 = 0; mt2 < 2; ++mt2)
#pragma unroll
            for (int nt2 = 0; nt2 < 2; ++nt2)
                o2[mt2][nt2] = __builtin_amdgcn_mfma_f32_16x16x32_bf16(af[mt2], pb[nt2], z4, 0, 0, 0);

        float ym[2][4];
#pragma unroll
        for (int mt2 = 0; mt2 < 2; ++mt2)
#pragma unroll
            for (int r = 0; r < 4; ++r)
                ym[mt2][r] = fmaxf(o2[mt2][0][r], o2[mt2][1][r]);
#pragma unroll
        for (int m = 1; m <= 8; m <<= 1)
#pragma unroll
            for (int mt2 = 0; mt2 < 2; ++mt2)
#pragma unroll
                for (int r = 0; r < 4; ++r)
                    ym[mt2][r] = fmaxf(ym[mt2][r], __shfl_xor(ym[mt2][r], m));
        if (lr == 0) {
#pragma unroll
            for (int mt2 = 0; mt2 < 2; ++mt2) {
                unsigned long long pk = 0;
#pragma unroll
                for (int r = 0; r < 4; ++r)
                    pk |= ((unsigned long long)f2b(ym[mt2][r])) << (16 * r);
                *(unsigned long long*)&y[(size_t)bn * 128 + h * 32 + mt2 * 16 + lg * 4] = pk;
            }
        }
    }
}

// ---------------------------------------------------------------------------
// zgemm: z = we_bf16 @ cat(y-x, x). MODE 0: bne stats; MODE 1: apply+write.
// ---------------------------------------------------------------------------
template <int MODE>
__global__ __launch_bounds__(256) void zgemm_kernel(
    const ushort_t* __restrict__ wb, const ushort_t* __restrict__ xT,
    const ushort_t* __restrict__ y, float* __restrict__ ws,
    const float* __restrict__ gamma, const float* __restrict__ beta,
    float* __restrict__ out)
{
    __shared__ __align__(16) ushort_t Bt[32 * 256];  // [bn-local][c] swizzled
    const int blk = blockIdx.x;                      // 256 blocks
    const int bn0 = blk * 32;
    const int t   = threadIdx.x;
    {
        const int r   = t >> 3;
        const int c0  = (t & 7) * 16;
        const int bnr = bn0 + r;
        const s8v* yr = (const s8v*)(y  + (size_t)bnr * 128 + c0);
        const s8v* xr = (const s8v*)(xT + (size_t)bnr * 128 + c0);
        const s8v y0 = yr[0], y1 = yr[1], x0 = xr[0], x1 = xr[1];
        s8v d0, d1;
#pragma unroll
        for (int j = 0; j < 8; ++j) {
            d0[j] = (short)f2b(b2f((ushort_t)y0[j]) - b2f((ushort_t)x0[j]));
            d1[j] = (short)f2b(b2f((ushort_t)y1[j]) - b2f((ushort_t)x1[j]));
        }
        const int sw = (r & 7) << 3;
        *(s8v*)&Bt[(r * 256 + c0) ^ sw]           = d0;
        *(s8v*)&Bt[(r * 256 + c0 + 8) ^ sw]       = d1;
        *(s8v*)&Bt[(r * 256 + 128 + c0) ^ sw]     = x0;
        *(s8v*)&Bt[(r * 256 + 128 + c0 + 8) ^ sw] = x1;
    }
    __syncthreads();

    const int w = t >> 6, l = t & 63, lr = l & 15, lg = l >> 4;
    const f4v z4 = {0.f, 0.f, 0.f, 0.f};
    f4v acc[4][2];
#pragma unroll
    for (int mt = 0; mt < 4; ++mt)
#pragma unroll
        for (int nt = 0; nt < 2; ++nt) acc[mt][nt] = z4;

#pragma unroll
    for (int kt = 0; kt < 8; ++kt) {
        const int kc = kt * 32 + lg * 8;
        bf16x8 bf[2];
#pragma unroll
        for (int nt = 0; nt < 2; ++nt) {
            const int rl = nt * 16 + lr;
            bf[nt] = ld8(&Bt[(rl * 256 + kc) ^ ((lr & 7) << 3)]);
        }
#pragma unroll
        for (int mt = 0; mt < 4; ++mt) {
            const int o = w * 64 + mt * 16 + lr;
            const bf16x8 am = ld8(&wb[WEB + o * 256 + kc]);
#pragma unroll
            for (int nt = 0; nt < 2; ++nt)
                acc[mt][nt] = __builtin_amdgcn_mfma_f32_16x16x32_bf16(am, bf[nt], acc[mt][nt], 0, 0, 0);
        }
    }

    if (MODE == 0) {
        float sm[4][4], sq[4][4];
#pragma unroll
        for (int mt = 0; mt < 4; ++mt)
#pragma unroll
            for (int r = 0; r < 4; ++r) {
                const float a0 = acc[mt][0][r], a1 = acc[mt][1][r];
                sm[mt][r] = a0 + a1;
                sq[mt][r] = a0 * a0 + a1 * a1;
            }
#pragma unroll
        for (int m = 1; m <= 8; m <<= 1)
#pragma unroll
            for (int mt = 0; mt < 4; ++mt)
#pragma unroll
                for (int r = 0; r < 4; ++r) {
                    sm[mt][r] += __shfl_xor(sm[mt][r], m);
                    sq[mt][r] += __shfl_xor(sq[mt][r], m);
                }
        if (lr == 0) {
#pragma unroll
            for (int mt = 0; mt < 4; ++mt)
#pragma unroll
                for (int r = 0; r < 4; ++r) {
                    const int o = w * 64 + mt * 16 + lg * 4 + r;
                    atomicAdd(&ws[WS_ESUM + o], sm[mt][r]);
                    atomicAdd(&ws[WS_ESS + o],  sq[mt][r]);
                }
        }
    } else {
        const int b = bn0 >> 10;
#pragma unroll
        for (int mt = 0; mt < 4; ++mt)
#pragma unroll
            for (int r = 0; r < 4; ++r) {
                const int o = w * 64 + mt * 16 + lg * 4 + r;
                const float mean = ws[WS_ESUM + o] * INV_BN;
                const float var  = ws[WS_ESS + o] * INV_BN - mean * mean;
                const float A  = gamma[o] * rsqrtf(var + EPSF);
                const float Bb = beta[o] - mean * A;
#pragma unroll
                for (int nt = 0; nt < 2; ++nt) {
                    const int n  = (bn0 + nt * 16 + lr) & (N_ - 1);
                    const float rv = A * acc[mt][nt][r] + Bb;
                    out[((size_t)(b * COUT + o)) * N_ + n] = rv >= 0.f ? rv : NEG * rv;
                }
            }
    }
}

// ---------------------------------------------------------------------------
extern "C" void kernel_launch(void* const* d_in, const int* in_sizes, int n_in,
                              void* d_out, int out_size, void* d_ws, size_t ws_size,
                              hipStream_t stream)
{
    (void)in_sizes; (void)n_in; (void)out_size; (void)ws_size;

    const float* x         = (const float*)d_in[0];
    const float* SiPF      = (const float*)d_in[1];
    const float* w_kv      = (const float*)d_in[2];
    const float* wk1       = (const float*)d_in[3];
    const float* bnk_gamma = (const float*)d_in[4];
    const float* bnk_beta  = (const float*)d_in[5];
    const float* wk2       = (const float*)d_in[6];
    const float* wv1       = (const float*)d_in[7];
    // d_in[8] = bv1: cancels inside _bn2d — unused
    const float* bnv_gamma = (const float*)d_in[9];
    const float* bnv_beta  = (const float*)d_in[10];
    const float* wv2       = (const float*)d_in[11];
    const float* bv2       = (const float*)d_in[12];
    const float* we        = (const float*)d_in[13];
    const float* bne_gamma = (const float*)d_in[14];
    const float* bne_beta  = (const float*)d_in[15];
    const int*   col       = (const int*)d_in[16];

    float*    ws = (float*)d_ws;
    ushort_t* wb = (ushort_t*)((char*)d_ws + WB_BYTE);
    ushort_t* xT = (ushort_t*)((char*)d_ws + XT_BYTE);
    ushort_t* y  = (ushort_t*)((char*)d_ws + Y_BYTE);

    hipMemsetAsync(d_ws, 0, 584 * sizeof(float), stream);

    prep_kernel<<<1216, 256, 0, stream>>>(x, SiPF, w_kv, wk2, wv2, we, ws, wb, xT);
    prep2_kernel<<<1, 128, 0, stream>>>(wk1, wv1, bnk_gamma, bnk_beta,
                                        bnv_gamma, bnv_beta, ws, wb);
    main_kernel<<<8192, 256, 0, stream>>>(SiPF, bv2, col, ws, wb, xT, y);
    zgemm_kernel<0><<<256, 256, 0, stream>>>(wb, xT, y, ws, bne_gamma, bne_beta,
                                             (float*)d_out);
    zgemm_kernel<1><<<256, 256, 0, stream>>>(wb, xT, y, ws, bne_gamma, bne_beta,
                                             (float*)d_out);
}